// Round 1
// baseline (1178.336 us; speedup 1.0000x reference)
//
#include <hip/hip_runtime.h>

// TransformerBlock on MI355X (gfx950).
// Pipeline: convert weights fp32->bf16 | LN1 | QKV GEMM | flash attn | O GEMM+resid
//           | LN2 | FF-up GEMM+relu | FF-down GEMM+resid -> out.
// All GEMMs: m97 structure (128x128 tile, BK=32, 4 waves, mfma_f32_16x16x32_bf16,
// global_load_lds width=16). fp32 accumulate everywhere.

#define D_MODEL 2048
#define N_HEADS 16
#define HEAD_DIM 128
#define DFF_DIM 8192
#define BATCH 2
#define SEQ 2048
#define M_TOK (BATCH*SEQ)  // 4096 tokens

typedef __attribute__((ext_vector_type(8))) __bf16 bf16x8;
typedef __attribute__((ext_vector_type(4))) float f32x4;

__device__ __forceinline__ unsigned short f2bf(float f) {
  union { float f; unsigned u; } v; v.f = f;
  unsigned r = v.u + 0x7fffu + ((v.u >> 16) & 1u);   // RNE
  return (unsigned short)(r >> 16);
}

__device__ __forceinline__ void gload_lds16(const void* g, void* l) {
  __builtin_amdgcn_global_load_lds(
      (const __attribute__((address_space(1))) unsigned int*)g,
      (__attribute__((address_space(3))) unsigned int*)l, 16, 0, 0);
}

// ---------------- fp32 -> bf16 convert ----------------
__global__ __launch_bounds__(256)
void f2bf_kernel(const float* __restrict__ in, unsigned short* __restrict__ out, long n) {
  long i = ((long)blockIdx.x * 256 + threadIdx.x) * 4;
  if (i < n) {
    float4 v = *(const float4*)&in[i];
    ushort4 r;
    r.x = f2bf(v.x); r.y = f2bf(v.y); r.z = f2bf(v.z); r.w = f2bf(v.w);
    *(ushort4*)&out[i] = r;
  }
}

// ---------------- LayerNorm (row=2048 fp32) -> bf16 ----------------
__global__ __launch_bounds__(256)
void ln_kernel(const float* __restrict__ x, const float* __restrict__ g,
               const float* __restrict__ b, unsigned short* __restrict__ out) {
  const int row = blockIdx.x, t = threadIdx.x;
  const float* xr = x + (long)row * D_MODEL;
  float4 v0 = *(const float4*)&xr[t * 8];
  float4 v1 = *(const float4*)&xr[t * 8 + 4];
  float s  = v0.x + v0.y + v0.z + v0.w + v1.x + v1.y + v1.z + v1.w;
  float ss = v0.x*v0.x + v0.y*v0.y + v0.z*v0.z + v0.w*v0.w
           + v1.x*v1.x + v1.y*v1.y + v1.z*v1.z + v1.w*v1.w;
  #pragma unroll
  for (int m = 1; m < 64; m <<= 1) { s += __shfl_xor(s, m); ss += __shfl_xor(ss, m); }
  __shared__ float red[8];
  if ((t & 63) == 0) { red[t >> 6] = s; red[4 + (t >> 6)] = ss; }
  __syncthreads();
  s  = red[0] + red[1] + red[2] + red[3];
  ss = red[4] + red[5] + red[6] + red[7];
  const float mu = s * (1.f / D_MODEL);
  const float var = ss * (1.f / D_MODEL) - mu * mu;
  const float rs = rsqrtf(var + 1e-5f);
  float xv[8];
  xv[0]=v0.x; xv[1]=v0.y; xv[2]=v0.z; xv[3]=v0.w; xv[4]=v1.x; xv[5]=v1.y; xv[6]=v1.z; xv[7]=v1.w;
  #pragma unroll
  for (int j = 0; j < 8; j++) {
    int c = t * 8 + j;
    out[(long)row * D_MODEL + c] = f2bf((xv[j] - mu) * rs * g[c] + b[c]);
  }
}

// ---------------- GEMM: C = A(bf16 MxK) * Bt(bf16 NxK)^T, m97 structure ----------------
// MODE 0: QKV scatter -> ob0/ob1/ob2 as [B,H,S,hd] bf16
// MODE 1: outf[r,c] = resid[r,c] + acc   (fp32, N must be 2048)
// MODE 2: ob0[r,c] = bf16(relu(acc))
template<int MODE>
__global__ __launch_bounds__(256)
void gemm_bt(const unsigned short* __restrict__ A, const unsigned short* __restrict__ Bt,
             int M, int N, int K,
             const float* __restrict__ resid, float* __restrict__ outf,
             unsigned short* __restrict__ ob0, unsigned short* __restrict__ ob1,
             unsigned short* __restrict__ ob2) {
  __shared__ __align__(16) unsigned short As[128 * 32];
  __shared__ __align__(16) unsigned short Bs[128 * 32];
  const int tid = threadIdx.x;
  const int w = tid >> 6, l = tid & 63;
  const int wr = w >> 1, wc = w & 1;
  const long m0 = (long)blockIdx.y * 128;
  const long n0 = (long)blockIdx.x * 128;

  f32x4 acc[4][4] = {};

  const int lrow = l >> 2;          // 0..15
  const int lcol = (l & 3) * 8;     // 0,8,16,24
  const unsigned short* Ag = A + (m0 + w * 16 + lrow) * (long)K + lcol;
  const unsigned short* Bg = Bt + (n0 + w * 16 + lrow) * (long)K + lcol;
  unsigned short* AsW = &As[(w * 16) * 32];  // wave-uniform LDS base
  unsigned short* BsW = &Bs[(w * 16) * 32];

  for (int k0 = 0; k0 < K; k0 += 32) {
    gload_lds16(Ag + k0,                AsW);
    gload_lds16(Ag + 64 * (long)K + k0, AsW + 64 * 32);
    gload_lds16(Bg + k0,                BsW);
    gload_lds16(Bg + 64 * (long)K + k0, BsW + 64 * 32);
    __syncthreads();
    bf16x8 af[4], bfr[4];
    #pragma unroll
    for (int mi = 0; mi < 4; mi++)
      af[mi] = *(const bf16x8*)&As[(wr * 64 + mi * 16 + (l & 15)) * 32 + (l >> 4) * 8];
    #pragma unroll
    for (int ni = 0; ni < 4; ni++)
      bfr[ni] = *(const bf16x8*)&Bs[(wc * 64 + ni * 16 + (l & 15)) * 32 + (l >> 4) * 8];
    #pragma unroll
    for (int mi = 0; mi < 4; mi++)
      #pragma unroll
      for (int ni = 0; ni < 4; ni++)
        acc[mi][ni] = __builtin_amdgcn_mfma_f32_16x16x32_bf16(af[mi], bfr[ni], acc[mi][ni], 0, 0, 0);
    __syncthreads();
  }

  // epilogue: C row = m0+wr*64+mi*16+(l>>4)*4+j ; col = n0+wc*64+ni*16+(l&15)
  #pragma unroll
  for (int mi = 0; mi < 4; mi++) {
    #pragma unroll
    for (int ni = 0; ni < 4; ni++) {
      #pragma unroll
      for (int j = 0; j < 4; j++) {
        long r = m0 + wr * 64 + mi * 16 + (l >> 4) * 4 + j;
        long c = n0 + wc * 64 + ni * 16 + (l & 15);
        float val = acc[mi][ni][j];
        if (MODE == 0) {
          int which = (int)(c >> 11);
          int cc = (int)(c & 2047);
          int hh = cc >> 7, dd = cc & 127;
          int bb = (int)(r >> 11), sp = (int)(r & 2047);
          long idx = ((long)(bb * N_HEADS + hh) * SEQ + sp) * HEAD_DIM + dd;
          unsigned short bv = f2bf(val);
          if (which == 0)      ob0[idx] = bv;
          else if (which == 1) ob1[idx] = bv;
          else                 ob2[idx] = bv;
        } else if (MODE == 1) {
          long idx = r * (long)N + c;
          outf[idx] = resid[idx] + val;
        } else {
          long idx = r * (long)N + c;
          ob0[idx] = f2bf(fmaxf(val, 0.f));
        }
      }
    }
  }
}

// ---------------- fused flash attention ----------------
// grid (S/64, H, B), 256 thr. Wave w owns q-rows [qb*64+w*16, +16). KV tiles of 32.
// K tile LDS [32][128] XOR-swizzled (pre-swizzled global source, G4/m173 pattern);
// V^T tile LDS [128][48] (padded, reg-transposed staging); P via per-wave [16][48] LDS.
__global__ __launch_bounds__(256)
void attn_kernel(const unsigned short* __restrict__ q, const unsigned short* __restrict__ k,
                 const unsigned short* __restrict__ v, unsigned short* __restrict__ o) {
  __shared__ __align__(16) unsigned short Kt[32 * 128];
  __shared__ __align__(16) unsigned short VT[128 * 48];
  __shared__ __align__(16) unsigned short Pl[4][16 * 48];
  const int tid = threadIdx.x, w = tid >> 6, l = tid & 63;
  const int b = blockIdx.z, h = blockIdx.y, qb = blockIdx.x;
  const long base = ((long)(b * N_HEADS + h)) * SEQ * HEAD_DIM;
  const unsigned short* qp = q + base;
  const unsigned short* kp = k + base;
  const unsigned short* vp = v + base;
  const int q0 = qb * 64 + w * 16;

  bf16x8 qf[4];
  #pragma unroll
  for (int kc = 0; kc < 4; kc++)
    qf[kc] = *(const bf16x8*)&qp[(q0 + (l & 15)) * HEAD_DIM + kc * 32 + (l >> 4) * 8];

  f32x4 oacc[8] = {};
  float mrow[4], lsum[4];
  #pragma unroll
  for (int j = 0; j < 4; j++) { mrow[j] = -1e30f; lsum[j] = 0.f; }

  const float sc = 0.08838834764831845f;  // 1/sqrt(128)

  for (int k0 = 0; k0 < SEQ; k0 += 32) {
    // stage K, swizzled source so linear LDS + swizzled reads match (m173)
    #pragma unroll
    for (int i = 0; i < 2; i++) {
      int row = i * 16 + w * 4 + (l >> 4);
      int sb = ((l & 15) * 16) ^ ((row & 7) << 4);
      gload_lds16((const char*)kp + (long)(k0 + row) * 256 + sb,
                  (char*)Kt + i * 4096 + w * 1024);
    }
    // stage V^T via register transpose
    {
      int r = tid >> 3, d0 = (tid & 7) * 16;
      const uint4* src = (const uint4*)&vp[(long)(k0 + r) * HEAD_DIM + d0];
      uint4 a = src[0], bb = src[1];
      unsigned short tmp[16];
      *(uint4*)&tmp[0] = a; *(uint4*)&tmp[8] = bb;
      #pragma unroll
      for (int j = 0; j < 16; j++) VT[(d0 + j) * 48 + r] = tmp[j];
    }
    __syncthreads();

    // QK^T: S[q][kcol], 2 col-tiles of 16
    f32x4 s[2] = {};
    #pragma unroll
    for (int kt = 0; kt < 2; kt++) {
      int kcol = kt * 16 + (l & 15);
      #pragma unroll
      for (int kc = 0; kc < 4; kc++) {
        int off = (kc * 64 + (l >> 4) * 16) ^ ((kcol & 7) << 4);
        bf16x8 kf = *(const bf16x8*)((const char*)Kt + kcol * 256 + off);
        s[kt] = __builtin_amdgcn_mfma_f32_16x16x32_bf16(qf[kc], kf, s[kt], 0, 0, 0);
      }
    }
    #pragma unroll
    for (int kt = 0; kt < 2; kt++)
      #pragma unroll
      for (int j = 0; j < 4; j++) s[kt][j] *= sc;

    // online softmax (rows j -> q = (l>>4)*4+j; reduce over 16 lanes = kcols)
    float pm[4];
    #pragma unroll
    for (int j = 0; j < 4; j++) pm[j] = fmaxf(s[0][j], s[1][j]);
    #pragma unroll
    for (int m = 1; m < 16; m <<= 1)
      #pragma unroll
      for (int j = 0; j < 4; j++) pm[j] = fmaxf(pm[j], __shfl_xor(pm[j], m));
    float alpha[4], p0[4], p1[4], ps[4];
    #pragma unroll
    for (int j = 0; j < 4; j++) {
      float mn = fmaxf(mrow[j], pm[j]);
      alpha[j] = __expf(mrow[j] - mn);
      mrow[j] = mn;
      p0[j] = __expf(s[0][j] - mn);
      p1[j] = __expf(s[1][j] - mn);
      ps[j] = p0[j] + p1[j];
    }
    #pragma unroll
    for (int m = 1; m < 16; m <<= 1)
      #pragma unroll
      for (int j = 0; j < 4; j++) ps[j] += __shfl_xor(ps[j], m);
    #pragma unroll
    for (int j = 0; j < 4; j++) lsum[j] = lsum[j] * alpha[j] + ps[j];
    #pragma unroll
    for (int n = 0; n < 8; n++)
      #pragma unroll
      for (int j = 0; j < 4; j++) oacc[n][j] *= alpha[j];

    // P -> per-wave LDS (bf16), conflict-free write pattern
    unsigned short* Pw = Pl[w];
    #pragma unroll
    for (int j = 0; j < 4; j++) {
      int qr = (l >> 4) * 4 + j;
      Pw[qr * 48 + (l & 15)]      = f2bf(p0[j]);
      Pw[qr * 48 + 16 + (l & 15)] = f2bf(p1[j]);
    }
    // PV: O[q][d] += P[16x32] * V[32x128]
    bf16x8 pa = *(const bf16x8*)&Pw[(l & 15) * 48 + (l >> 4) * 8];
    #pragma unroll
    for (int n = 0; n < 8; n++) {
      bf16x8 vf = *(const bf16x8*)&VT[(n * 16 + (l & 15)) * 48 + (l >> 4) * 8];
      oacc[n] = __builtin_amdgcn_mfma_f32_16x16x32_bf16(pa, vf, oacc[n], 0, 0, 0);
    }
    __syncthreads();
  }

  #pragma unroll
  for (int j = 0; j < 4; j++) lsum[j] = 1.f / lsum[j];
  #pragma unroll
  for (int n = 0; n < 8; n++)
    #pragma unroll
    for (int j = 0; j < 4; j++) {
      int sp = q0 + (l >> 4) * 4 + j;
      int d = n * 16 + (l & 15);
      o[((long)b * SEQ + sp) * D_MODEL + h * HEAD_DIM + d] = f2bf(oacc[n][j] * lsum[j]);
    }
}

// ---------------- launcher ----------------
extern "C" void kernel_launch(void* const* d_in, const int* in_sizes, int n_in,
                              void* d_out, int out_size, void* d_ws, size_t ws_size,
                              hipStream_t stream) {
  (void)in_sizes; (void)n_in; (void)out_size; (void)ws_size;
  const float* x   = (const float*)d_in[0];
  const float* wq  = (const float*)d_in[1];
  const float* wk  = (const float*)d_in[2];
  const float* wv  = (const float*)d_in[3];
  const float* wo  = (const float*)d_in[4];
  const float* wup = (const float*)d_in[5];
  const float* wdn = (const float*)d_in[6];
  const float* g1  = (const float*)d_in[7];
  const float* b1  = (const float*)d_in[8];
  const float* g2  = (const float*)d_in[9];
  const float* b2  = (const float*)d_in[10];
  float* out = (float*)d_out;

  char* ws = (char*)d_ws;
  size_t off = 0;
  unsigned short* wqkv = (unsigned short*)(ws + off); off += (size_t)3 * D_MODEL * D_MODEL * 2;
  unsigned short* wo_b = (unsigned short*)(ws + off); off += (size_t)D_MODEL * D_MODEL * 2;
  unsigned short* wup_b = (unsigned short*)(ws + off); off += (size_t)DFF_DIM * D_MODEL * 2;
  unsigned short* wdn_b = (unsigned short*)(ws + off); off += (size_t)DFF_DIM * D_MODEL * 2;
  unsigned short* h_b  = (unsigned short*)(ws + off); off += (size_t)M_TOK * D_MODEL * 2;
  unsigned short* q_b  = (unsigned short*)(ws + off); off += (size_t)M_TOK * D_MODEL * 2;
  unsigned short* k_b  = (unsigned short*)(ws + off); off += (size_t)M_TOK * D_MODEL * 2;
  unsigned short* v_b  = (unsigned short*)(ws + off); off += (size_t)M_TOK * D_MODEL * 2;
  unsigned short* ao_b = (unsigned short*)(ws + off); off += (size_t)M_TOK * D_MODEL * 2;
  float* x1            = (float*)(ws + off);          off += (size_t)M_TOK * D_MODEL * 4;
  unsigned short* ffu  = q_b;  // alias: q/k/v/ao are dead before FF-up writes (needs 64MB = q..ao span)

  const long nW = (long)D_MODEL * D_MODEL;      // 4.19M
  const long nU = (long)DFF_DIM * D_MODEL;      // 16.8M
  f2bf_kernel<<<nW / 1024, 256, 0, stream>>>(wq, wqkv, nW);
  f2bf_kernel<<<nW / 1024, 256, 0, stream>>>(wk, wqkv + nW, nW);
  f2bf_kernel<<<nW / 1024, 256, 0, stream>>>(wv, wqkv + 2 * nW, nW);
  f2bf_kernel<<<nW / 1024, 256, 0, stream>>>(wo, wo_b, nW);
  f2bf_kernel<<<nU / 1024, 256, 0, stream>>>(wup, wup_b, nU);
  f2bf_kernel<<<nU / 1024, 256, 0, stream>>>(wdn, wdn_b, nU);

  ln_kernel<<<M_TOK, 256, 0, stream>>>(x, g1, b1, h_b);

  gemm_bt<0><<<dim3(48, 32), 256, 0, stream>>>(h_b, wqkv, M_TOK, 3 * D_MODEL, D_MODEL,
                                               nullptr, nullptr, q_b, k_b, v_b);

  attn_kernel<<<dim3(SEQ / 64, N_HEADS, BATCH), 256, 0, stream>>>(q_b, k_b, v_b, ao_b);

  gemm_bt<1><<<dim3(16, 32), 256, 0, stream>>>(ao_b, wo_b, M_TOK, D_MODEL, D_MODEL,
                                               x, x1, nullptr, nullptr, nullptr);

  ln_kernel<<<M_TOK, 256, 0, stream>>>(x1, g2, b2, h_b);

  gemm_bt<2><<<dim3(64, 32), 256, 0, stream>>>(h_b, wup_b, M_TOK, DFF_DIM, D_MODEL,
                                               nullptr, nullptr, ffu, nullptr, nullptr);

  gemm_bt<1><<<dim3(16, 32), 256, 0, stream>>>(ffu, wdn_b, M_TOK, D_MODEL, DFF_DIM,
                                               x1, out, nullptr, nullptr, nullptr);
}

// Round 4
// 1047.749 us; speedup vs baseline: 1.1246x; 1.1246x over previous
//
#include <hip/hip_runtime.h>

// TransformerBlock on MI355X (gfx950).
// R2 (resubmit x2): attention reworked — V^T produced by QKV GEMM ([B,H,hd,S]),
// conflict-free LDS tiles (Kt[32][128] XOR-swizzled, VT[128][32] linear, P stride-40),
// 8-wave/128-q blocks, 2-phase double-buffered staging with counted vmcnt,
// defer-max online softmax (THR=8).
// GEMMs: m97 structure (128x128 tile, BK=32, 4 waves, mfma_f32_16x16x32_bf16).

#define D_MODEL 2048
#define N_HEADS 16
#define HEAD_DIM 128
#define DFF_DIM 8192
#define BATCH 2
#define SEQ 2048
#define M_TOK (BATCH*SEQ)  // 4096 tokens

typedef __attribute__((ext_vector_type(8))) __bf16 bf16x8;
typedef __attribute__((ext_vector_type(4))) float f32x4;

__device__ __forceinline__ unsigned short f2bf(float f) {
  union { float f; unsigned u; } v; v.f = f;
  unsigned r = v.u + 0x7fffu + ((v.u >> 16) & 1u);   // RNE
  return (unsigned short)(r >> 16);
}

__device__ __forceinline__ void gload_lds16(const void* g, void* l) {
  __builtin_amdgcn_global_load_lds(
      (const __attribute__((address_space(1))) unsigned int*)g,
      (__attribute__((address_space(3))) unsigned int*)l, 16, 0, 0);
}

// ---------------- fp32 -> bf16 convert ----------------
__global__ __launch_bounds__(256)
void f2bf_kernel(const float* __restrict__ in, unsigned short* __restrict__ out, long n) {
  long i = ((long)blockIdx.x * 256 + threadIdx.x) * 4;
  if (i < n) {
    float4 v = *(const float4*)&in[i];
    ushort4 r;
    r.x = f2bf(v.x); r.y = f2bf(v.y); r.z = f2bf(v.z); r.w = f2bf(v.w);
    *(ushort4*)&out[i] = r;
  }
}

// ---------------- LayerNorm (row=2048 fp32) -> bf16 ----------------
__global__ __launch_bounds__(256)
void ln_kernel(const float* __restrict__ x, const float* __restrict__ g,
               const float* __restrict__ b, unsigned short* __restrict__ out) {
  const int row = blockIdx.x, t = threadIdx.x;
  const float* xr = x + (long)row * D_MODEL;
  float4 v0 = *(const float4*)&xr[t * 8];
  float4 v1 = *(const float4*)&xr[t * 8 + 4];
  float s  = v0.x + v0.y + v0.z + v0.w + v1.x + v1.y + v1.z + v1.w;
  float ss = v0.x*v0.x + v0.y*v0.y + v0.z*v0.z + v0.w*v0.w
           + v1.x*v1.x + v1.y*v1.y + v1.z*v1.z + v1.w*v1.w;
  #pragma unroll
  for (int m = 1; m < 64; m <<= 1) { s += __shfl_xor(s, m); ss += __shfl_xor(ss, m); }
  __shared__ float red[8];
  if ((t & 63) == 0) { red[t >> 6] = s; red[4 + (t >> 6)] = ss; }
  __syncthreads();
  s  = red[0] + red[1] + red[2] + red[3];
  ss = red[4] + red[5] + red[6] + red[7];
  const float mu = s * (1.f / D_MODEL);
  const float var = ss * (1.f / D_MODEL) - mu * mu;
  const float rs = rsqrtf(var + 1e-5f);
  float xv[8];
  xv[0]=v0.x; xv[1]=v0.y; xv[2]=v0.z; xv[3]=v0.w; xv[4]=v1.x; xv[5]=v1.y; xv[6]=v1.z; xv[7]=v1.w;
  #pragma unroll
  for (int j = 0; j < 8; j++) {
    int c = t * 8 + j;
    out[(long)row * D_MODEL + c] = f2bf((xv[j] - mu) * rs * g[c] + b[c]);
  }
}

// ---------------- GEMM: C = A(bf16 MxK) * Bt(bf16 NxK)^T, m97 structure ----------------
// MODE 0: QKV scatter -> ob0/ob1 as [B,H,S,hd] bf16; ob2 (V) as [B,H,hd,S] (V^T)
// MODE 1: outf[r,c] = resid[r,c] + acc   (fp32)
// MODE 2: ob0[r,c] = bf16(relu(acc))
template<int MODE>
__global__ __launch_bounds__(256)
void gemm_bt(const unsigned short* __restrict__ A, const unsigned short* __restrict__ Bt,
             int M, int N, int K,
             const float* __restrict__ resid, float* __restrict__ outf,
             unsigned short* __restrict__ ob0, unsigned short* __restrict__ ob1,
             unsigned short* __restrict__ ob2) {
  __shared__ __align__(16) unsigned short As[128 * 32];
  __shared__ __align__(16) unsigned short Bs[128 * 32];
  const int tid = threadIdx.x;
  const int w = tid >> 6, l = tid & 63;
  const int wr = w >> 1, wc = w & 1;
  const long m0 = (long)blockIdx.y * 128;
  const long n0 = (long)blockIdx.x * 128;

  f32x4 acc[4][4] = {};

  const int lrow = l >> 2;          // 0..15
  const int lcol = (l & 3) * 8;     // 0,8,16,24
  const unsigned short* Ag = A + (m0 + w * 16 + lrow) * (long)K + lcol;
  const unsigned short* Bg = Bt + (n0 + w * 16 + lrow) * (long)K + lcol;
  unsigned short* AsW = &As[(w * 16) * 32];  // wave-uniform LDS base
  unsigned short* BsW = &Bs[(w * 16) * 32];

  for (int k0 = 0; k0 < K; k0 += 32) {
    gload_lds16(Ag + k0,                AsW);
    gload_lds16(Ag + 64 * (long)K + k0, AsW + 64 * 32);
    gload_lds16(Bg + k0,                BsW);
    gload_lds16(Bg + 64 * (long)K + k0, BsW + 64 * 32);
    __syncthreads();
    bf16x8 af[4], bfr[4];
    #pragma unroll
    for (int mi = 0; mi < 4; mi++)
      af[mi] = *(const bf16x8*)&As[(wr * 64 + mi * 16 + (l & 15)) * 32 + (l >> 4) * 8];
    #pragma unroll
    for (int ni = 0; ni < 4; ni++)
      bfr[ni] = *(const bf16x8*)&Bs[(wc * 64 + ni * 16 + (l & 15)) * 32 + (l >> 4) * 8];
    #pragma unroll
    for (int mi = 0; mi < 4; mi++)
      #pragma unroll
      for (int ni = 0; ni < 4; ni++)
        acc[mi][ni] = __builtin_amdgcn_mfma_f32_16x16x32_bf16(af[mi], bfr[ni], acc[mi][ni], 0, 0, 0);
    __syncthreads();
  }

  // epilogue: C row = m0+wr*64+mi*16+(l>>4)*4+j ; col = n0+wc*64+ni*16+(l&15)
  #pragma unroll
  for (int mi = 0; mi < 4; mi++) {
    #pragma unroll
    for (int ni = 0; ni < 4; ni++) {
      long c = n0 + wc * 64 + ni * 16 + (l & 15);
      long r0 = m0 + wr * 64 + mi * 16 + (l >> 4) * 4;
      if (MODE == 0) {
        int which = (int)(c >> 11);
        int cc = (int)(c & 2047);
        int hh = cc >> 7, dd = cc & 127;
        int bb = (int)(r0 >> 11), sp = (int)(r0 & 2047);
        if (which == 2) {
          // V^T: [B,H,hd,S]; 4 consecutive sp -> packed 8B store
          ushort4 pk;
          pk.x = f2bf(acc[mi][ni][0]); pk.y = f2bf(acc[mi][ni][1]);
          pk.z = f2bf(acc[mi][ni][2]); pk.w = f2bf(acc[mi][ni][3]);
          *(ushort4*)&ob2[((long)(bb * N_HEADS + hh) * HEAD_DIM + dd) * SEQ + sp] = pk;
        } else {
          #pragma unroll
          for (int j = 0; j < 4; j++) {
            long idx = ((long)(bb * N_HEADS + hh) * SEQ + sp + j) * HEAD_DIM + dd;
            unsigned short bv = f2bf(acc[mi][ni][j]);
            if (which == 0) ob0[idx] = bv; else ob1[idx] = bv;
          }
        }
      } else if (MODE == 1) {
        #pragma unroll
        for (int j = 0; j < 4; j++) {
          long idx = (r0 + j) * (long)N + c;
          outf[idx] = resid[idx] + acc[mi][ni][j];
        }
      } else {
        #pragma unroll
        for (int j = 0; j < 4; j++) {
          long idx = (r0 + j) * (long)N + c;
          ob0[idx] = f2bf(fmaxf(acc[mi][ni][j], 0.f));
        }
      }
    }
  }
}

// ---------------- fused flash attention (R2) ----------------
// grid (S/128, H, B), 512 thr (8 waves). Wave w owns q-rows [qb*128+w*16, +16).
// KV tiles of 32. Kt[2][32][128] XOR-swizzled via pre-swizzled global source;
// VT[2][128][32] staged linearly from V^T global (64B rows -> conflict-floor reads);
// P per-wave [16][40] (2-way writes, slot-bijective reads).
// 2-phase pipeline: STAGE(next); vmcnt(2); barrier; compute(cur); barrier.
__global__ __launch_bounds__(512)
void attn_kernel(const unsigned short* __restrict__ q, const unsigned short* __restrict__ k,
                 const unsigned short* __restrict__ vt, unsigned short* __restrict__ o) {
  __shared__ __align__(16) unsigned short Kt[2][32 * 128];
  __shared__ __align__(16) unsigned short VT[2][128 * 32];
  __shared__ __align__(16) unsigned short Pl[8][16 * 40];
  const int tid = threadIdx.x, w = tid >> 6, l = tid & 63;
  const int b = blockIdx.z, h = blockIdx.y, qb = blockIdx.x;
  const long base = ((long)(b * N_HEADS + h)) * SEQ * HEAD_DIM;
  const unsigned short* qp = q + base + (long)(qb * 128) * HEAD_DIM;
  const unsigned short* kp = k + base;
  const unsigned short* vp = vt + base;   // [hd][S]
  const int hi = l >> 4, lr = l & 15;

  bf16x8 qf[4];
  #pragma unroll
  for (int kc = 0; kc < 4; kc++)
    qf[kc] = *(const bf16x8*)&qp[(w * 16 + lr) * HEAD_DIM + kc * 32 + hi * 8];

  f32x4 oacc[8] = {};
  float mrow[4], lsum[4];
  #pragma unroll
  for (int j = 0; j < 4; j++) { mrow[j] = -1e30f; lsum[j] = 0.f; }

  const float sc = 0.08838834764831845f;  // 1/sqrt(128)
  const int NT = SEQ / 32;

  // staging: per wave 1 K-instr (rows w*4..w*4+3) + 1 V-instr (d rows w*16..+15)
  const int krow = w * 4 + hi;
  const long ksrc_off = (long)krow * 256 + (((l & 15) * 16) ^ ((krow & 7) << 4));
  const int vd = w * 16 + (l >> 2);
  const long vsrc_off = (long)vd * (SEQ * 2) + (l & 3) * 16;

  // prologue: stage tile 0 into buf 0
  gload_lds16((const char*)kp + ksrc_off, (char*)Kt[0] + w * 1024);
  gload_lds16((const char*)vp + vsrc_off, (char*)VT[0] + w * 1024);

  int cur = 0;
  for (int t = 0; t < NT; t++) {
    if (t < NT - 1) {
      const long k0b = (long)(t + 1) * 64;  // 32 S-positions * 2B along V^T rows
      gload_lds16((const char*)kp + (t + 1) * (32 * 256) + ksrc_off, (char*)Kt[cur ^ 1] + w * 1024);
      gload_lds16((const char*)vp + k0b + vsrc_off,                  (char*)VT[cur ^ 1] + w * 1024);
      asm volatile("s_waitcnt vmcnt(2)" ::: "memory");
    } else {
      asm volatile("s_waitcnt vmcnt(0)" ::: "memory");
    }
    __builtin_amdgcn_s_barrier();

    const unsigned short* Kc = Kt[cur];
    const unsigned short* Vc = VT[cur];

    // QK^T: S[q][kcol], 2 col-tiles of 16
    f32x4 s[2] = {};
    #pragma unroll
    for (int kt = 0; kt < 2; kt++) {
      int kcol = kt * 16 + lr;
      #pragma unroll
      for (int kc = 0; kc < 4; kc++) {
        int off = (kc * 64 + hi * 16) ^ ((kcol & 7) << 4);
        bf16x8 kf = *(const bf16x8*)((const char*)Kc + kcol * 256 + off);
        s[kt] = __builtin_amdgcn_mfma_f32_16x16x32_bf16(qf[kc], kf, s[kt], 0, 0, 0);
      }
    }
    #pragma unroll
    for (int kt = 0; kt < 2; kt++)
      #pragma unroll
      for (int j = 0; j < 4; j++) s[kt][j] *= sc;

    // online softmax, defer-max (THR=8)
    float pm[4];
    #pragma unroll
    for (int j = 0; j < 4; j++) pm[j] = fmaxf(s[0][j], s[1][j]);
    #pragma unroll
    for (int m = 1; m < 16; m <<= 1)
      #pragma unroll
      for (int j = 0; j < 4; j++) pm[j] = fmaxf(pm[j], __shfl_xor(pm[j], m));
    int need = 0;
    #pragma unroll
    for (int j = 0; j < 4; j++) need |= (pm[j] > mrow[j] + 8.0f);
    if (__any(need)) {
      #pragma unroll
      for (int j = 0; j < 4; j++) {
        float nm = fmaxf(mrow[j], pm[j]);
        float alpha = __expf(mrow[j] - nm);
        mrow[j] = nm;
        lsum[j] *= alpha;
        #pragma unroll
        for (int n = 0; n < 8; n++) oacc[n][j] *= alpha;
      }
    }
    float p0[4], p1[4], ps[4];
    #pragma unroll
    for (int j = 0; j < 4; j++) {
      p0[j] = __expf(s[0][j] - mrow[j]);
      p1[j] = __expf(s[1][j] - mrow[j]);
      ps[j] = p0[j] + p1[j];
    }
    #pragma unroll
    for (int m = 1; m < 16; m <<= 1)
      #pragma unroll
      for (int j = 0; j < 4; j++) ps[j] += __shfl_xor(ps[j], m);
    #pragma unroll
    for (int j = 0; j < 4; j++) lsum[j] += ps[j];

    // P -> per-wave LDS (bf16), stride 40
    unsigned short* Pw = Pl[w];
    #pragma unroll
    for (int j = 0; j < 4; j++) {
      int qr = hi * 4 + j;
      Pw[qr * 40 + lr]      = f2bf(p0[j]);
      Pw[qr * 40 + 16 + lr] = f2bf(p1[j]);
    }
    // PV: O[q][d] += P[16x32] * V[32x128]
    bf16x8 pa = *(const bf16x8*)&Pw[lr * 40 + hi * 8];
    #pragma unroll
    for (int n = 0; n < 8; n++) {
      bf16x8 vf = *(const bf16x8*)&Vc[(n * 16 + lr) * 32 + hi * 8];
      oacc[n] = __builtin_amdgcn_mfma_f32_16x16x32_bf16(pa, vf, oacc[n], 0, 0, 0);
    }
    __builtin_amdgcn_s_barrier();
    cur ^= 1;
  }

  float rls[4];
  #pragma unroll
  for (int j = 0; j < 4; j++) rls[j] = 1.f / lsum[j];
  #pragma unroll
  for (int n = 0; n < 8; n++)
    #pragma unroll
    for (int j = 0; j < 4; j++) {
      int sp = qb * 128 + w * 16 + hi * 4 + j;
      int d = n * 16 + lr;
      o[((long)b * SEQ + sp) * D_MODEL + h * HEAD_DIM + d] = f2bf(oacc[n][j] * rls[j]);
    }
}

// ---------------- launcher ----------------
extern "C" void kernel_launch(void* const* d_in, const int* in_sizes, int n_in,
                              void* d_out, int out_size, void* d_ws, size_t ws_size,
                              hipStream_t stream) {
  (void)in_sizes; (void)n_in; (void)out_size; (void)ws_size;
  const float* x   = (const float*)d_in[0];
  const float* wq  = (const float*)d_in[1];
  const float* wk  = (const float*)d_in[2];
  const float* wv  = (const float*)d_in[3];
  const float* wo  = (const float*)d_in[4];
  const float* wup = (const float*)d_in[5];
  const float* wdn = (const float*)d_in[6];
  const float* g1  = (const float*)d_in[7];
  const float* b1  = (const float*)d_in[8];
  const float* g2  = (const float*)d_in[9];
  const float* b2  = (const float*)d_in[10];
  float* out = (float*)d_out;

  char* ws = (char*)d_ws;
  size_t off = 0;
  unsigned short* wqkv = (unsigned short*)(ws + off); off += (size_t)3 * D_MODEL * D_MODEL * 2;
  unsigned short* wo_b = (unsigned short*)(ws + off); off += (size_t)D_MODEL * D_MODEL * 2;
  unsigned short* wup_b = (unsigned short*)(ws + off); off += (size_t)DFF_DIM * D_MODEL * 2;
  unsigned short* wdn_b = (unsigned short*)(ws + off); off += (size_t)DFF_DIM * D_MODEL * 2;
  unsigned short* h_b  = (unsigned short*)(ws + off); off += (size_t)M_TOK * D_MODEL * 2;
  unsigned short* q_b  = (unsigned short*)(ws + off); off += (size_t)M_TOK * D_MODEL * 2;
  unsigned short* k_b  = (unsigned short*)(ws + off); off += (size_t)M_TOK * D_MODEL * 2;
  unsigned short* v_b  = (unsigned short*)(ws + off); off += (size_t)M_TOK * D_MODEL * 2;  // holds V^T [B,H,hd,S]
  unsigned short* ao_b = (unsigned short*)(ws + off); off += (size_t)M_TOK * D_MODEL * 2;
  float* x1            = (float*)(ws + off);          off += (size_t)M_TOK * D_MODEL * 4;
  unsigned short* ffu  = q_b;  // alias: q/k/v/ao dead before FF-up writes

  const long nW = (long)D_MODEL * D_MODEL;      // 4.19M
  const long nU = (long)DFF_DIM * D_MODEL;      // 16.8M
  f2bf_kernel<<<nW / 1024, 256, 0, stream>>>(wq, wqkv, nW);
  f2bf_kernel<<<nW / 1024, 256, 0, stream>>>(wk, wqkv + nW, nW);
  f2bf_kernel<<<nW / 1024, 256, 0, stream>>>(wv, wqkv + 2 * nW, nW);
  f2bf_kernel<<<nW / 1024, 256, 0, stream>>>(wo, wo_b, nW);
  f2bf_kernel<<<nU / 1024, 256, 0, stream>>>(wup, wup_b, nU);
  f2bf_kernel<<<nU / 1024, 256, 0, stream>>>(wdn, wdn_b, nU);

  ln_kernel<<<M_TOK, 256, 0, stream>>>(x, g1, b1, h_b);

  gemm_bt<0><<<dim3(48, 32), 256, 0, stream>>>(h_b, wqkv, M_TOK, 3 * D_MODEL, D_MODEL,
                                               nullptr, nullptr, q_b, k_b, v_b);

  attn_kernel<<<dim3(SEQ / 128, N_HEADS, BATCH), 512, 0, stream>>>(q_b, k_b, v_b, ao_b);

  gemm_bt<1><<<dim3(16, 32), 256, 0, stream>>>(ao_b, wo_b, M_TOK, D_MODEL, D_MODEL,
                                               x, x1, nullptr, nullptr, nullptr);

  ln_kernel<<<M_TOK, 256, 0, stream>>>(x1, g2, b2, h_b);

  gemm_bt<2><<<dim3(64, 32), 256, 0, stream>>>(h_b, wup_b, M_TOK, DFF_DIM, D_MODEL,
                                               nullptr, nullptr, ffu, nullptr, nullptr);

  gemm_bt<1><<<dim3(16, 32), 256, 0, stream>>>(ffu, wdn_b, M_TOK, D_MODEL, DFF_DIM,
                                               x1, out, nullptr, nullptr, nullptr);
}

// Round 7
// 1014.120 us; speedup vs baseline: 1.1619x; 1.0332x over previous
//
#include <hip/hip_runtime.h>

// TransformerBlock on MI355X (gfx950).
// R5 (resubmit x2): QKV + FF-up GEMMs on the 256x256 8-phase template (T3+T4
// counted-vmcnt pipeline, T2 XOR-swizzled LDS, T5 setprio, T1 XCD-bijective
// block swizzle), BK=32 variant (64 KB LDS, double-buffered, vmcnt(2)).
// FF-down + O-proj stay on the m97 128x128 structure; attention unchanged from R2.

#define D_MODEL 2048
#define N_HEADS 16
#define HEAD_DIM 128
#define DFF_DIM 8192
#define BATCH 2
#define SEQ 2048
#define M_TOK (BATCH*SEQ)  // 4096 tokens

typedef __attribute__((ext_vector_type(8))) __bf16 bf16x8;
typedef __attribute__((ext_vector_type(4))) float f32x4;

struct FalseT { static constexpr bool value = false; };
struct TrueT  { static constexpr bool value = true;  };

__device__ __forceinline__ unsigned short f2bf(float f) {
  union { float f; unsigned u; } v; v.f = f;
  unsigned r = v.u + 0x7fffu + ((v.u >> 16) & 1u);   // RNE
  return (unsigned short)(r >> 16);
}

__device__ __forceinline__ void gload_lds16(const void* g, void* l) {
  __builtin_amdgcn_global_load_lds(
      (const __attribute__((address_space(1))) unsigned int*)g,
      (__attribute__((address_space(3))) unsigned int*)l, 16, 0, 0);
}

#define BAR __builtin_amdgcn_s_barrier()
#define LG0 asm volatile("s_waitcnt lgkmcnt(0)" ::: "memory")
#define VMW(n) asm volatile("s_waitcnt vmcnt(" #n ")" ::: "memory")
#define PRIO1 __builtin_amdgcn_s_setprio(1)
#define PRIO0 __builtin_amdgcn_s_setprio(0)

// ---------------- fp32 -> bf16 convert ----------------
__global__ __launch_bounds__(256)
void f2bf_kernel(const float* __restrict__ in, unsigned short* __restrict__ out, long n) {
  long i = ((long)blockIdx.x * 256 + threadIdx.x) * 4;
  if (i < n) {
    float4 v = *(const float4*)&in[i];
    ushort4 r;
    r.x = f2bf(v.x); r.y = f2bf(v.y); r.z = f2bf(v.z); r.w = f2bf(v.w);
    *(ushort4*)&out[i] = r;
  }
}

// ---------------- LayerNorm (row=2048 fp32) -> bf16 ----------------
__global__ __launch_bounds__(256)
void ln_kernel(const float* __restrict__ x, const float* __restrict__ g,
               const float* __restrict__ b, unsigned short* __restrict__ out) {
  const int row = blockIdx.x, t = threadIdx.x;
  const float* xr = x + (long)row * D_MODEL;
  float4 v0 = *(const float4*)&xr[t * 8];
  float4 v1 = *(const float4*)&xr[t * 8 + 4];
  float s  = v0.x + v0.y + v0.z + v0.w + v1.x + v1.y + v1.z + v1.w;
  float ss = v0.x*v0.x + v0.y*v0.y + v0.z*v0.z + v0.w*v0.w
           + v1.x*v1.x + v1.y*v1.y + v1.z*v1.z + v1.w*v1.w;
  #pragma unroll
  for (int m = 1; m < 64; m <<= 1) { s += __shfl_xor(s, m); ss += __shfl_xor(ss, m); }
  __shared__ float red[8];
  if ((t & 63) == 0) { red[t >> 6] = s; red[4 + (t >> 6)] = ss; }
  __syncthreads();
  s  = red[0] + red[1] + red[2] + red[3];
  ss = red[4] + red[5] + red[6] + red[7];
  const float mu = s * (1.f / D_MODEL);
  const float var = ss * (1.f / D_MODEL) - mu * mu;
  const float rs = rsqrtf(var + 1e-5f);
  float xv[8];
  xv[0]=v0.x; xv[1]=v0.y; xv[2]=v0.z; xv[3]=v0.w; xv[4]=v1.x; xv[5]=v1.y; xv[6]=v1.z; xv[7]=v1.w;
  #pragma unroll
  for (int j = 0; j < 8; j++) {
    int c = t * 8 + j;
    out[(long)row * D_MODEL + c] = f2bf((xv[j] - mu) * rs * g[c] + b[c]);
  }
}

// ---------------- m97 GEMM (kept for O-proj, FF-down) ----------------
// MODE 1: outf[r,c] = resid[r,c] + acc   (fp32)
template<int MODE>
__global__ __launch_bounds__(256)
void gemm_bt(const unsigned short* __restrict__ A, const unsigned short* __restrict__ Bt,
             int M, int N, int K,
             const float* __restrict__ resid, float* __restrict__ outf,
             unsigned short* __restrict__ ob0) {
  __shared__ __align__(16) unsigned short As[128 * 32];
  __shared__ __align__(16) unsigned short Bs[128 * 32];
  const int tid = threadIdx.x;
  const int w = tid >> 6, l = tid & 63;
  const int wr = w >> 1, wc = w & 1;
  const long m0 = (long)blockIdx.y * 128;
  const long n0 = (long)blockIdx.x * 128;

  f32x4 acc[4][4] = {};

  const int lrow = l >> 2;
  const int lcol = (l & 3) * 8;
  const unsigned short* Ag = A + (m0 + w * 16 + lrow) * (long)K + lcol;
  const unsigned short* Bg = Bt + (n0 + w * 16 + lrow) * (long)K + lcol;
  unsigned short* AsW = &As[(w * 16) * 32];
  unsigned short* BsW = &Bs[(w * 16) * 32];

  for (int k0 = 0; k0 < K; k0 += 32) {
    gload_lds16(Ag + k0,                AsW);
    gload_lds16(Ag + 64 * (long)K + k0, AsW + 64 * 32);
    gload_lds16(Bg + k0,                BsW);
    gload_lds16(Bg + 64 * (long)K + k0, BsW + 64 * 32);
    __syncthreads();
    bf16x8 af[4], bfr[4];
    #pragma unroll
    for (int mi = 0; mi < 4; mi++)
      af[mi] = *(const bf16x8*)&As[(wr * 64 + mi * 16 + (l & 15)) * 32 + (l >> 4) * 8];
    #pragma unroll
    for (int ni = 0; ni < 4; ni++)
      bfr[ni] = *(const bf16x8*)&Bs[(wc * 64 + ni * 16 + (l & 15)) * 32 + (l >> 4) * 8];
    #pragma unroll
    for (int mi = 0; mi < 4; mi++)
      #pragma unroll
      for (int ni = 0; ni < 4; ni++)
        acc[mi][ni] = __builtin_amdgcn_mfma_f32_16x16x32_bf16(af[mi], bfr[ni], acc[mi][ni], 0, 0, 0);
    __syncthreads();
  }

  #pragma unroll
  for (int mi = 0; mi < 4; mi++) {
    #pragma unroll
    for (int ni = 0; ni < 4; ni++) {
      long c = n0 + wc * 64 + ni * 16 + (l & 15);
      long r0 = m0 + wr * 64 + mi * 16 + (l >> 4) * 4;
      if (MODE == 1) {
        #pragma unroll
        for (int j = 0; j < 4; j++) {
          long idx = (r0 + j) * (long)N + c;
          outf[idx] = resid[idx] + acc[mi][ni][j];
        }
      } else {
        #pragma unroll
        for (int j = 0; j < 4; j++) {
          long idx = (r0 + j) * (long)N + c;
          ob0[idx] = f2bf(fmaxf(acc[mi][ni][j], 0.f));
        }
      }
    }
  }
}

// ---------------- 256x256 8-phase GEMM (BK=32 variant) ----------------
// See R5 comments: 8 waves (2Mx4N), LDS 64 KB double-buffered, XOR-swizzle
// byte ^= ((r>>1)&3)<<4 applied on read + pre-applied on staging source.
// Staging: p1:A0(o) p2:A1(o) p3:B0(e+2) p4:B1(e+2)+VM(2)
//          p5:A0(e+2) p6:A1(e+2) p7:B0(o+2) p8:B1(o+2)+VM(2)
// Hazard ledger audited R5/R6 (WAR: stage >=1 barrier after last ds_read of
// that buffer; vmcnt(2) retires exactly the needed K-tile at each boundary).
// MODE 0: QKV scatter (Q,K -> [B,H,S,hd]; V -> V^T [B,H,hd,S]).
// MODE 2: ob0 = bf16(relu(acc)).
template<int MODE>
__global__ __launch_bounds__(512, 2)
void gemm256(const unsigned short* __restrict__ A, const unsigned short* __restrict__ Bt,
             int N, int K, const float* __restrict__ resid, float* __restrict__ outf,
             unsigned short* __restrict__ ob0, unsigned short* __restrict__ ob1,
             unsigned short* __restrict__ ob2) {
  __shared__ __align__(16) char ldsc[65536];
  const int tid = threadIdx.x;
  const int w  = tid >> 6, l = tid & 63;
  const int wm = w >> 2, wn = w & 3;
  const int lr = l & 15, hi = l >> 4;

  // T1: XCD-bijective tile swizzle (ntiles % 8 == 0), M-fastest tile order.
  const int ntiles = gridDim.x;
  const int cpx = ntiles >> 3;
  const int tile = ((int)blockIdx.x & 7) * cpx + ((int)blockIdx.x >> 3);
  const int ty = tile & 15;        // grid_m = 16 (M = 4096)
  const int tx = tile >> 4;
  const long m0 = (long)ty * 256;
  const long n0 = (long)tx * 256;

  f32x4 acc[8][4] = {};
  bf16x8 a_r[4], b0_r[2], b1_r[2];

  // staging source (pre-swizzled): thread covers row s_row of a 128x32 half-tile
  const int s_row  = w * 16 + (l >> 2);
  const int s_colx = ((l & 3) * 16) ^ (((s_row >> 1) & 3) << 4);   // byte in 64B row
  const char* Abase = (const char*)A + ((m0 + s_row) * (long)K) * 2 + s_colx;
  const char* Bbase = (const char*)Bt + ((n0 + s_row) * (long)K) * 2 + s_colx;
  const size_t Kh = (size_t)K * 256;   // 128 rows of K bf16, bytes

  auto stgA = [&](int d, int h, int t) {
    gload_lds16(Abase + (size_t)h * Kh + (size_t)t * 64,
                ldsc + (d * 2 + h) * 8192 + w * 1024);
  };
  auto stgB = [&](int d, int h, int t) {
    gload_lds16(Bbase + (size_t)h * Kh + (size_t)t * 64,
                ldsc + 32768 + (d * 2 + h) * 8192 + w * 1024);
  };

  // ds-read lane base (swizzled); per-(d,mh/nh,frag) offsets are immediates
  const int rd_base = lr * 64 + ((hi * 16) ^ (((lr >> 1) & 3) << 4));
  const char* ldsA = ldsc + wm * 8192 + rd_base;
  const char* ldsB = ldsc + 32768 + (wn >> 1) * 8192 + (wn & 1) * 4096 + rd_base;

  auto ldA = [&](int d, int mh) {
    #pragma unroll
    for (int i2 = 0; i2 < 4; i2++)
      a_r[i2] = *(const bf16x8*)(ldsA + d * 16384 + mh * 4096 + i2 * 1024);
  };
  auto ldB = [&](int d, int nh, bf16x8* dst) {
    #pragma unroll
    for (int i2 = 0; i2 < 2; i2++)
      dst[i2] = *(const bf16x8*)(ldsB + d * 16384 + nh * 2048 + i2 * 1024);
  };
  auto mf = [&](int mh, int nh, const bf16x8* b) {
    #pragma unroll
    for (int mi2 = 0; mi2 < 4; mi2++)
      #pragma unroll
      for (int ni2 = 0; ni2 < 2; ni2++)
        acc[mh * 4 + mi2][nh * 2 + ni2] = __builtin_amdgcn_mfma_f32_16x16x32_bf16(
            a_r[mi2], b[ni2], acc[mh * 4 + mi2][nh * 2 + ni2], 0, 0, 0);
  };

  // prologue: K-tile 0 fully staged + B(1) in flight
  stgA(0, 0, 0); stgA(0, 1, 0); stgB(0, 0, 0); stgB(0, 1, 0);
  stgB(1, 0, 1); stgB(1, 1, 1);
  VMW(2); BAR;

  auto iter = [&](int e, auto last_c) {
    constexpr bool L = decltype(last_c)::value;
    // p1
    ldA(0, 0); ldB(0, 0, b0_r); stgA(1, 0, e + 1);
    BAR; LG0; PRIO1; mf(0, 0, b0_r); PRIO0; BAR;
    // p2
    ldB(0, 1, b1_r); stgA(1, 1, e + 1);
    BAR; LG0; PRIO1; mf(0, 1, b1_r); PRIO0; BAR;
    // p3
    ldA(0, 1); if constexpr (!L) stgB(0, 0, e + 2);
    BAR; LG0; PRIO1; mf(1, 0, b0_r); PRIO0; BAR;
    // p4 (K-tile boundary)
    if constexpr (!L) { stgB(0, 1, e + 2); VMW(2); } else { VMW(0); }
    BAR; PRIO1; mf(1, 1, b1_r); PRIO0; BAR;
    // p5
    ldA(1, 0); ldB(1, 0, b0_r); if constexpr (!L) stgA(0, 0, e + 2);
    BAR; LG0; PRIO1; mf(0, 0, b0_r); PRIO0; BAR;
    // p6
    ldB(1, 1, b1_r); if constexpr (!L) stgA(0, 1, e + 2);
    BAR; LG0; PRIO1; mf(0, 1, b1_r); PRIO0; BAR;
    // p7
    ldA(1, 1); if constexpr (!L) stgB(1, 0, e + 3);
    BAR; LG0; PRIO1; mf(1, 0, b0_r); PRIO0; BAR;
    // p8 (K-tile boundary)
    if constexpr (!L) { stgB(1, 1, e + 3); VMW(2); }
    BAR; PRIO1; mf(1, 1, b1_r); PRIO0; BAR;
  };

  const int NITER = K >> 6;   // 2 K-tiles (BK=32) per iteration
  for (int it = 0; it < NITER - 1; it++) iter(2 * it, FalseT{});
  iter(2 * (NITER - 1), TrueT{});

  // epilogue: row = m0 + wm*128 + mh*64 + mi*16 + hi*4 + j
  //           col = n0 + wn*64 + nh*32 + ni*16 + lr
  #pragma unroll
  for (int a = 0; a < 8; a++) {
    const int mh = a >> 2, mi = a & 3;
    #pragma unroll
    for (int bq = 0; bq < 4; bq++) {
      const int nh = bq >> 1, ni = bq & 1;
      long c  = n0 + wn * 64 + nh * 32 + ni * 16 + lr;
      long r0 = m0 + wm * 128 + mh * 64 + mi * 16 + hi * 4;
      if (MODE == 0) {
        int which = (int)(c >> 11);
        int cc = (int)(c & 2047);
        int hh = cc >> 7, dd = cc & 127;
        int bb = (int)(r0 >> 11), sp = (int)(r0 & 2047);
        if (which == 2) {
          ushort4 pk;
          pk.x = f2bf(acc[a][bq][0]); pk.y = f2bf(acc[a][bq][1]);
          pk.z = f2bf(acc[a][bq][2]); pk.w = f2bf(acc[a][bq][3]);
          *(ushort4*)&ob2[((long)(bb * N_HEADS + hh) * HEAD_DIM + dd) * SEQ + sp] = pk;
        } else {
          #pragma unroll
          for (int j = 0; j < 4; j++) {
            long idx = ((long)(bb * N_HEADS + hh) * SEQ + sp + j) * HEAD_DIM + dd;
            unsigned short bv = f2bf(acc[a][bq][j]);
            if (which == 0) ob0[idx] = bv; else ob1[idx] = bv;
          }
        }
      } else {
        #pragma unroll
        for (int j = 0; j < 4; j++)
          ob0[(r0 + j) * (long)N + c] = f2bf(fmaxf(acc[a][bq][j], 0.f));
      }
    }
  }
  (void)resid; (void)outf;
}

// ---------------- fused flash attention (unchanged from R2) ----------------
__global__ __launch_bounds__(512)
void attn_kernel(const unsigned short* __restrict__ q, const unsigned short* __restrict__ k,
                 const unsigned short* __restrict__ vt, unsigned short* __restrict__ o) {
  __shared__ __align__(16) unsigned short Kt[2][32 * 128];
  __shared__ __align__(16) unsigned short VT[2][128 * 32];
  __shared__ __align__(16) unsigned short Pl[8][16 * 40];
  const int tid = threadIdx.x, w = tid >> 6, l = tid & 63;
  const int b = blockIdx.z, h = blockIdx.y, qb = blockIdx.x;
  const long base = ((long)(b * N_HEADS + h)) * SEQ * HEAD_DIM;
  const unsigned short* qp = q + base + (long)(qb * 128) * HEAD_DIM;
  const unsigned short* kp = k + base;
  const unsigned short* vp = vt + base;   // [hd][S]
  const int hi = l >> 4, lr = l & 15;

  bf16x8 qf[4];
  #pragma unroll
  for (int kc = 0; kc < 4; kc++)
    qf[kc] = *(const bf16x8*)&qp[(w * 16 + lr) * HEAD_DIM + kc * 32 + hi * 8];

  f32x4 oacc[8] = {};
  float mrow[4], lsum[4];
  #pragma unroll
  for (int j = 0; j < 4; j++) { mrow[j] = -1e30f; lsum[j] = 0.f; }

  const float sc = 0.08838834764831845f;  // 1/sqrt(128)
  const int NT = SEQ / 32;

  const int krow = w * 4 + hi;
  const long ksrc_off = (long)krow * 256 + (((l & 15) * 16) ^ ((krow & 7) << 4));
  const int vd = w * 16 + (l >> 2);
  const long vsrc_off = (long)vd * (SEQ * 2) + (l & 3) * 16;

  gload_lds16((const char*)kp + ksrc_off, (char*)Kt[0] + w * 1024);
  gload_lds16((const char*)vp + vsrc_off, (char*)VT[0] + w * 1024);

  int cur = 0;
  for (int t = 0; t < NT; t++) {
    if (t < NT - 1) {
      const long k0b = (long)(t + 1) * 64;
      gload_lds16((const char*)kp + (t + 1) * (32 * 256) + ksrc_off, (char*)Kt[cur ^ 1] + w * 1024);
      gload_lds16((const char*)vp + k0b + vsrc_off,                  (char*)VT[cur ^ 1] + w * 1024);
      VMW(2);
    } else {
      VMW(0);
    }
    __builtin_amdgcn_s_barrier();

    const unsigned short* Kc = Kt[cur];
    const unsigned short* Vc = VT[cur];

    f32x4 s[2] = {};
    #pragma unroll
    for (int kt = 0; kt < 2; kt++) {
      int kcol = kt * 16 + lr;
      #pragma unroll
      for (int kc = 0; kc < 4; kc++) {
        int off = (kc * 64 + hi * 16) ^ ((kcol & 7) << 4);
        bf16x8 kf = *(const bf16x8*)((const char*)Kc + kcol * 256 + off);
        s[kt] = __builtin_amdgcn_mfma_f32_16x16x32_bf16(qf[kc], kf, s[kt], 0, 0, 0);
      }
    }
    #pragma unroll
    for (int kt = 0; kt < 2; kt++)
      #pragma unroll
      for (int j = 0; j < 4; j++) s[kt][j] *= sc;

    float pm[4];
    #pragma unroll
    for (int j = 0; j < 4; j++) pm[j] = fmaxf(s[0][j], s[1][j]);
    #pragma unroll
    for (int m = 1; m < 16; m <<= 1)
      #pragma unroll
      for (int j = 0; j < 4; j++) pm[j] = fmaxf(pm[j], __shfl_xor(pm[j], m));
    int need = 0;
    #pragma unroll
    for (int j = 0; j < 4; j++) need |= (pm[j] > mrow[j] + 8.0f);
    if (__any(need)) {
      #pragma unroll
      for (int j = 0; j < 4; j++) {
        float nm = fmaxf(mrow[j], pm[j]);
        float alpha = __expf(mrow[j] - nm);
        mrow[j] = nm;
        lsum[j] *= alpha;
        #pragma unroll
        for (int n = 0; n < 8; n++) oacc[n][j] *= alpha;
      }
    }
    float p0[4], p1[4], ps[4];
    #pragma unroll
    for (int j = 0; j < 4; j++) {
      p0[j] = __expf(s[0][j] - mrow[j]);
      p1[j] = __expf(s[1][j] - mrow[j]);
      ps[j] = p0[j] + p1[j];
    }
    #pragma unroll
    for (int m = 1; m < 16; m <<= 1)
      #pragma unroll
      for (int j = 0; j < 4; j++) ps[j] += __shfl_xor(ps[j], m);
    #pragma unroll
    for (int j = 0; j < 4; j++) lsum[j] += ps[j];

    unsigned short* Pw = Pl[w];
    #pragma unroll
    for (int j = 0; j < 4; j++) {
      int qr = hi * 4 + j;
      Pw[qr * 40 + lr]      = f2bf(p0[j]);
      Pw[qr * 40 + 16 + lr] = f2bf(p1[j]);
    }
    bf16x8 pa = *(const bf16x8*)&Pw[lr * 40 + hi * 8];
    #pragma unroll
    for (int n = 0; n < 8; n++) {
      bf16x8 vf = *(const bf16x8*)&Vc[(n * 16 + lr) * 32 + hi * 8];
      oacc[n] = __builtin_amdgcn_mfma_f32_16x16x32_bf16(pa, vf, oacc[n], 0, 0, 0);
    }
    __builtin_amdgcn_s_barrier();
    cur ^= 1;
  }

  float rls[4];
  #pragma unroll
  for (int j = 0; j < 4; j++) rls[j] = 1.f / lsum[j];
  #pragma unroll
  for (int n = 0; n < 8; n++)
    #pragma unroll
    for (int j = 0; j < 4; j++) {
      int sp = qb * 128 + w * 16 + hi * 4 + j;
      int d = n * 16 + lr;
      o[((long)b * SEQ + sp) * D_MODEL + h * HEAD_DIM + d] = f2bf(oacc[n][j] * rls[j]);
    }
}

// ---------------- launcher ----------------
extern "C" void kernel_launch(void* const* d_in, const int* in_sizes, int n_in,
                              void* d_out, int out_size, void* d_ws, size_t ws_size,
                              hipStream_t stream) {
  (void)in_sizes; (void)n_in; (void)out_size; (void)ws_size;
  const float* x   = (const float*)d_in[0];
  const float* wq  = (const float*)d_in[1];
  const float* wk  = (const float*)d_in[2];
  const float* wv  = (const float*)d_in[3];
  const float* wo  = (const float*)d_in[4];
  const float* wup = (const float*)d_in[5];
  const float* wdn = (const float*)d_in[6];
  const float* g1  = (const float*)d_in[7];
  const float* b1  = (const float*)d_in[8];
  const float* g2  = (const float*)d_in[9];
  const float* b2  = (const float*)d_in[10];
  float* out = (float*)d_out;

  char* ws = (char*)d_ws;
  size_t off = 0;
  unsigned short* wqkv = (unsigned short*)(ws + off); off += (size_t)3 * D_MODEL * D_MODEL * 2;
  unsigned short* wo_b = (unsigned short*)(ws + off); off += (size_t)D_MODEL * D_MODEL * 2;
  unsigned short* wup_b = (unsigned short*)(ws + off); off += (size_t)DFF_DIM * D_MODEL * 2;
  unsigned short* wdn_b = (unsigned short*)(ws + off); off += (size_t)DFF_DIM * D_MODEL * 2;
  unsigned short* h_b  = (unsigned short*)(ws + off); off += (size_t)M_TOK * D_MODEL * 2;
  unsigned short* q_b  = (unsigned short*)(ws + off); off += (size_t)M_TOK * D_MODEL * 2;
  unsigned short* k_b  = (unsigned short*)(ws + off); off += (size_t)M_TOK * D_MODEL * 2;
  unsigned short* v_b  = (unsigned short*)(ws + off); off += (size_t)M_TOK * D_MODEL * 2;  // V^T [B,H,hd,S]
  unsigned short* ao_b = (unsigned short*)(ws + off); off += (size_t)M_TOK * D_MODEL * 2;
  float* x1            = (float*)(ws + off);          off += (size_t)M_TOK * D_MODEL * 4;
  unsigned short* ffu  = q_b;  // alias: q/k/v/ao dead before FF-up writes

  const long nW = (long)D_MODEL * D_MODEL;      // 4.19M
  const long nU = (long)DFF_DIM * D_MODEL;      // 16.8M
  f2bf_kernel<<<nW / 1024, 256, 0, stream>>>(wq, wqkv, nW);
  f2bf_kernel<<<nW / 1024, 256, 0, stream>>>(wk, wqkv + nW, nW);
  f2bf_kernel<<<nW / 1024, 256, 0, stream>>>(wv, wqkv + 2 * nW, nW);
  f2bf_kernel<<<nW / 1024, 256, 0, stream>>>(wo, wo_b, nW);
  f2bf_kernel<<<nU / 1024, 256, 0, stream>>>(wup, wup_b, nU);
  f2bf_kernel<<<nU / 1024, 256, 0, stream>>>(wdn, wdn_b, nU);

  ln_kernel<<<M_TOK, 256, 0, stream>>>(x, g1, b1, h_b);

  // QKV: M=4096, N=6144, K=2048 -> 24x16 = 384 tiles of 256^2
  gemm256<0><<<384, 512, 0, stream>>>(h_b, wqkv, 3 * D_MODEL, D_MODEL,
                                      nullptr, nullptr, q_b, k_b, v_b);

  attn_kernel<<<dim3(SEQ / 128, N_HEADS, BATCH), 512, 0, stream>>>(q_b, k_b, v_b, ao_b);

  gemm_bt<1><<<dim3(16, 32), 256, 0, stream>>>(ao_b, wo_b, M_TOK, D_MODEL, D_MODEL,
                                               x, x1, nullptr);

  ln_kernel<<<M_TOK, 256, 0, stream>>>(x1, g2, b2, h_b);

  // FF-up: M=4096, N=8192, K=2048 -> 32x16 = 512 tiles of 256^2
  gemm256<2><<<512, 512, 0, stream>>>(h_b, wup_b, DFF_DIM, D_MODEL,
                                      nullptr, nullptr, ffu, nullptr, nullptr);

  gemm_bt<1><<<dim3(16, 32), 256, 0, stream>>>(ffu, wdn_b, M_TOK, D_MODEL, DFF_DIM,
                                               x1, out, nullptr);
}

// Round 11
// 882.014 us; speedup vs baseline: 1.3360x; 1.1498x over previous
//
#include <hip/hip_runtime.h>

// TransformerBlock on MI355X (gfx950).
// R8 (resubmit x3): all four GEMMs on a faithful m201 256x256 8-phase template:
// BK=64, 128 KB LDS double-buffered, 2 global_load_lds per phase, vmcnt(6) at
// phase 4/8 only (3 half-tiles in flight), XOR-swizzle byte^=(row&7)<<4, setprio
// around MFMA, XCD-bijective tile swizzle. O-proj + FF-down use split-K=2
// (grid.y) with partials into dead ws buffers + addk merge. Attention from R2.

#define D_MODEL 2048
#define N_HEADS 16
#define HEAD_DIM 128
#define DFF_DIM 8192
#define BATCH 2
#define SEQ 2048
#define M_TOK (BATCH*SEQ)  // 4096 tokens

typedef __attribute__((ext_vector_type(8))) __bf16 bf16x8;
typedef __attribute__((ext_vector_type(4))) float f32x4;

struct FalseT { static constexpr bool value = false; };
struct TrueT  { static constexpr bool value = true;  };

__device__ __forceinline__ unsigned short f2bf(float f) {
  union { float f; unsigned u; } v; v.f = f;
  unsigned r = v.u + 0x7fffu + ((v.u >> 16) & 1u);   // RNE
  return (unsigned short)(r >> 16);
}

__device__ __forceinline__ void gload_lds16(const void* g, void* l) {
  __builtin_amdgcn_global_load_lds(
      (const __attribute__((address_space(1))) unsigned int*)g,
      (__attribute__((address_space(3))) unsigned int*)l, 16, 0, 0);
}

#define BAR __builtin_amdgcn_s_barrier()
#define LG0 asm volatile("s_waitcnt lgkmcnt(0)" ::: "memory")
#define VMW(n) asm volatile("s_waitcnt vmcnt(" #n ")" ::: "memory")
#define PRIO1 __builtin_amdgcn_s_setprio(1)
#define PRIO0 __builtin_amdgcn_s_setprio(0)

// ---------------- fp32 -> bf16 convert ----------------
__global__ __launch_bounds__(256)
void f2bf_kernel(const float* __restrict__ in, unsigned short* __restrict__ out, long n) {
  long i = ((long)blockIdx.x * 256 + threadIdx.x) * 4;
  if (i < n) {
    float4 v = *(const float4*)&in[i];
    ushort4 r;
    r.x = f2bf(v.x); r.y = f2bf(v.y); r.z = f2bf(v.z); r.w = f2bf(v.w);
    *(ushort4*)&out[i] = r;
  }
}

// ---------------- dst[i] += src[i] (fp32, float4) ----------------
__global__ __launch_bounds__(256)
void addk_kernel(float* __restrict__ dst, const float* __restrict__ src) {
  long i = ((long)blockIdx.x * 256 + threadIdx.x) * 4;
  float4 d = *(float4*)&dst[i];
  float4 s = *(const float4*)&src[i];
  d.x += s.x; d.y += s.y; d.z += s.z; d.w += s.w;
  *(float4*)&dst[i] = d;
}

// ---------------- LayerNorm (row=2048 fp32) -> bf16 ----------------
__global__ __launch_bounds__(256)
void ln_kernel(const float* __restrict__ x, const float* __restrict__ g,
               const float* __restrict__ b, unsigned short* __restrict__ out) {
  const int row = blockIdx.x, t = threadIdx.x;
  const float* xr = x + (long)row * D_MODEL;
  float4 v0 = *(const float4*)&xr[t * 8];
  float4 v1 = *(const float4*)&xr[t * 8 + 4];
  float s  = v0.x + v0.y + v0.z + v0.w + v1.x + v1.y + v1.z + v1.w;
  float ss = v0.x*v0.x + v0.y*v0.y + v0.z*v0.z + v0.w*v0.w
           + v1.x*v1.x + v1.y*v1.y + v1.z*v1.z + v1.w*v1.w;
  #pragma unroll
  for (int m = 1; m < 64; m <<= 1) { s += __shfl_xor(s, m); ss += __shfl_xor(ss, m); }
  __shared__ float red[8];
  if ((t & 63) == 0) { red[t >> 6] = s; red[4 + (t >> 6)] = ss; }
  __syncthreads();
  s  = red[0] + red[1] + red[2] + red[3];
  ss = red[4] + red[5] + red[6] + red[7];
  const float mu = s * (1.f / D_MODEL);
  const float var = ss * (1.f / D_MODEL) - mu * mu;
  const float rs = rsqrtf(var + 1e-5f);
  float xv[8];
  xv[0]=v0.x; xv[1]=v0.y; xv[2]=v0.z; xv[3]=v0.w; xv[4]=v1.x; xv[5]=v1.y; xv[6]=v1.z; xv[7]=v1.w;
  #pragma unroll
  for (int j = 0; j < 8; j++) {
    int c = t * 8 + j;
    out[(long)row * D_MODEL + c] = f2bf((xv[j] - mu) * rs * g[c] + b[c]);
  }
}

// ---------------- 256x256 8-phase GEMM, BK=64 (m201-faithful) ----------------
// C = A(4096 x K) * Bt(N x K)^T, bf16 in, fp32 acc. grid_m fixed 16.
// 512 thr = 8 waves (2M x 4N); per-wave out 128x64; acc[8][4] f32x4 (128 VGPR).
// LDS 128 KB: A[d][half][128 rows][64 cols] at d*32768+h*16384; B at +65536.
// Rows are 128 B; XOR-swizzle byte ^= (row&7)<<4 (2-way = free on b128 reads),
// pre-applied on the global staging source, applied again on ds_read (rule #21).
// Per K-tile (64): 4 quadrant phases (mh,nh): q1 reads A(mh0) 8 + B(nh0) 4
// b128, q2 reads B(nh1) 4, q3 reads A(mh1) 8, q4 reads none (regs held).
// Stage order (one half-tile = 2 gloads/phase; e even tile -> d0, o=e+1 -> d1):
//   p1: A1(o)   p2: B0(e+2)  p3: B1(e+2)  p4: A0(e+2)+VMW(6)
//   p5: A1(e+2) p6: B0(e+3)  p7: B1(e+3)  p8: A0(e+3)+VMW(6)
// Retire ledger (steady state, carry-in 6 = {B0,B1,A0}(o)): at p4 outstanding
// 14 -> VMW(6) retires {B0,B1,A0,A1}(o) = d1 resident for p5-p8; at p8
// retires {B0,B1,A0,A1}(e+2) = d0 resident for next p1-p4. WAR: every stage
// lands >=1 barrier after that buffer's last ds_read (B0(d0)@p1, B1(d0)@p2,
// A(d0)@p3, B0(d1)@p5, B1(d1)@p6, A(d1)@p7). Last iter: stages suppressed,
// VMW(0) at p4, no p8 wait. Prologue stages 7 half-tiles, VMW(6).
// MODE 0: QKV scatter (Q,K -> [B,H,S,hd]; V -> V^T [B,H,hd,S]).
// MODE 2: ob0 = bf16(relu(acc)).
// MODE 3: split-K via blockIdx.y: y==0 -> outf = resid + acc; y==1 -> pk = acc.
template<int MODE>
__global__ __launch_bounds__(512, 2)
void gemm256(const unsigned short* __restrict__ A, const unsigned short* __restrict__ Bt,
             int N, int Kstride, int Kext,
             const float* __restrict__ resid, float* __restrict__ outf,
             float* __restrict__ pk,
             unsigned short* __restrict__ ob0, unsigned short* __restrict__ ob1,
             unsigned short* __restrict__ ob2) {
  __shared__ __align__(16) char ldsc[131072];
  const int tid = threadIdx.x;
  const int w  = tid >> 6, l = tid & 63;
  const int wm = w >> 2, wn = w & 3;
  const int lr = l & 15, hi = l >> 4;

  // T1: XCD-bijective tile swizzle (gridDim.x % 8 == 0 for all our grids)
  const int cpx = (int)gridDim.x >> 3;
  const int tile = ((int)blockIdx.x & 7) * cpx + ((int)blockIdx.x >> 3);
  const int ty = tile & 15;          // grid_m = 16 (M = 4096)
  const int tx = tile >> 4;
  const long m0 = (long)ty * 256;
  const long n0 = (long)tx * 256;
  const long koff = (long)blockIdx.y * Kext;

  f32x4 acc[8][4] = {};
  bf16x8 a_r[8], b0_r[4], b1_r[4];

  // staging source (pre-swizzled). thread t covers row trow of a 64-row slab.
  const int trow = tid >> 3;                              // 0..63
  const int tcol = ((tid & 7) * 16) ^ ((trow & 7) << 4);  // byte in 128B row
  const char* pA = (const char*)A + ((m0 + trow) * (long)Kstride + koff) * 2 + tcol;
  const char* pB = (const char*)Bt + ((n0 + trow) * (long)Kstride + koff) * 2 + tcol;
  const size_t rowK = (size_t)Kstride * 2;                // bytes per row

  auto STGA = [&](int d, int h, int kt) {   // one half-tile = 2 gloads
    const char* s = pA + (size_t)(h * 128) * rowK + (size_t)kt * 128;
    char* dst = ldsc + d * 32768 + h * 16384 + w * 1024;
    gload_lds16(s, dst);
    gload_lds16(s + 64 * rowK, dst + 8192);
  };
  auto STGB = [&](int d, int h, int kt) {
    const char* s = pB + (size_t)(h * 128) * rowK + (size_t)kt * 128;
    char* dst = ldsc + 65536 + d * 32768 + h * 16384 + w * 1024;
    gload_lds16(s, dst);
    gload_lds16(s + 64 * rowK, dst + 8192);
  };

  // ds-read lane bases (one per ks, XOR is not additive with ks bit)
  const int xor0 = (hi * 16) ^ ((lr & 7) << 4);
  const int xor1 = (64 + hi * 16) ^ ((lr & 7) << 4);
  const char* lA0 = ldsc + wm * 16384 + lr * 128 + xor0;
  const char* lA1 = ldsc + wm * 16384 + lr * 128 + xor1;
  const char* lB0 = ldsc + 65536 + (wn >> 1) * 16384 + (wn & 1) * 8192 + lr * 128 + xor0;
  const char* lB1 = ldsc + 65536 + (wn >> 1) * 16384 + (wn & 1) * 8192 + lr * 128 + xor1;

  auto LDA = [&](int d, int mh) {
    #pragma unroll
    for (int mi = 0; mi < 4; mi++) {
      a_r[mi * 2 + 0] = *(const bf16x8*)(lA0 + d * 32768 + mh * 8192 + mi * 2048);
      a_r[mi * 2 + 1] = *(const bf16x8*)(lA1 + d * 32768 + mh * 8192 + mi * 2048);
    }
  };
  auto LDB = [&](int d, int nh, bf16x8* br) {
    #pragma unroll
    for (int ni = 0; ni < 2; ni++) {
      br[ni * 2 + 0] = *(const bf16x8*)(lB0 + d * 32768 + nh * 4096 + ni * 2048);
      br[ni * 2 + 1] = *(const bf16x8*)(lB1 + d * 32768 + nh * 4096 + ni * 2048);
    }
  };
  auto MF = [&](int mh, int nh, const bf16x8* br) {
    PRIO1;
    #pragma unroll
    for (int mi = 0; mi < 4; mi++)
      #pragma unroll
      for (int ni = 0; ni < 2; ni++) {
        f32x4 c = acc[mh * 4 + mi][nh * 2 + ni];
        c = __builtin_amdgcn_mfma_f32_16x16x32_bf16(a_r[mi * 2 + 0], br[ni * 2 + 0], c, 0, 0, 0);
        c = __builtin_amdgcn_mfma_f32_16x16x32_bf16(a_r[mi * 2 + 1], br[ni * 2 + 1], c, 0, 0, 0);
        acc[mh * 4 + mi][nh * 2 + ni] = c;
      }
    PRIO0;
  };

  // prologue: K-tile 0 (4 half-tiles) + B0,B1,A0 of K-tile 1 (issue order = FIFO)
  STGA(0, 0, 0); STGA(0, 1, 0); STGB(0, 0, 0); STGB(0, 1, 0);
  STGB(1, 0, 1); STGB(1, 1, 1); STGA(1, 0, 1);
  VMW(6); BAR;

  auto iter = [&](int e, auto lastc) {
    constexpr bool L = decltype(lastc)::value;
    // p1 (q1 of d0): A(mh0), B(nh0)
    LDA(0, 0); LDB(0, 0, b0_r); STGA(1, 1, e + 1);
    BAR; LG0; MF(0, 0, b0_r); BAR;
    // p2 (q2): B(nh1)
    LDB(0, 1, b1_r); if constexpr (!L) STGB(0, 0, e + 2);
    BAR; LG0; MF(0, 1, b1_r); BAR;
    // p3 (q3): A(mh1)
    LDA(0, 1); if constexpr (!L) STGB(0, 1, e + 2);
    BAR; LG0; MF(1, 0, b0_r); BAR;
    // p4 (q4): regs only; K-tile boundary
    if constexpr (!L) { STGA(0, 0, e + 2); VMW(6); } else { VMW(0); }
    BAR; MF(1, 1, b1_r); BAR;
    // p5 (q1 of d1)
    LDA(1, 0); LDB(1, 0, b0_r); if constexpr (!L) STGA(0, 1, e + 2);
    BAR; LG0; MF(0, 0, b0_r); BAR;
    // p6 (q2)
    LDB(1, 1, b1_r); if constexpr (!L) STGB(1, 0, e + 3);
    BAR; LG0; MF(0, 1, b1_r); BAR;
    // p7 (q3)
    LDA(1, 1); if constexpr (!L) STGB(1, 1, e + 3);
    BAR; LG0; MF(1, 0, b0_r); BAR;
    // p8 (q4); K-tile boundary
    if constexpr (!L) { STGA(1, 0, e + 3); VMW(6); }
    BAR; MF(1, 1, b1_r); BAR;
  };

  const int NITER = Kext >> 7;   // 2 K-tiles (BK=64) per iteration
  for (int it = 0; it < NITER - 1; it++) iter(2 * it, FalseT{});
  iter(2 * (NITER - 1), TrueT{});

  // epilogue: row = m0 + wm*128 + mh*64 + mi*16 + hi*4 + j
  //           col = n0 + wn*64 + nh*32 + ni*16 + lr
  #pragma unroll
  for (int a = 0; a < 8; a++) {
    const int mh = a >> 2, mi = a & 3;
    #pragma unroll
    for (int bq = 0; bq < 4; bq++) {
      const int nh = bq >> 1, ni = bq & 1;
      long c  = n0 + wn * 64 + nh * 32 + ni * 16 + lr;
      long r0 = m0 + wm * 128 + mh * 64 + mi * 16 + hi * 4;
      if (MODE == 0) {
        int which = (int)(c >> 11);
        int cc = (int)(c & 2047);
        int hh = cc >> 7, dd = cc & 127;
        int bb = (int)(r0 >> 11), sp = (int)(r0 & 2047);
        if (which == 2) {
          ushort4 pkv;
          pkv.x = f2bf(acc[a][bq][0]); pkv.y = f2bf(acc[a][bq][1]);
          pkv.z = f2bf(acc[a][bq][2]); pkv.w = f2bf(acc[a][bq][3]);
          *(ushort4*)&ob2[((long)(bb * N_HEADS + hh) * HEAD_DIM + dd) * SEQ + sp] = pkv;
        } else {
          #pragma unroll
          for (int j = 0; j < 4; j++) {
            long idx = ((long)(bb * N_HEADS + hh) * SEQ + sp + j) * HEAD_DIM + dd;
            unsigned short bv = f2bf(acc[a][bq][j]);
            if (which == 0) ob0[idx] = bv; else ob1[idx] = bv;
          }
        }
      } else if (MODE == 2) {
        #pragma unroll
        for (int j = 0; j < 4; j++)
          ob0[(r0 + j) * (long)N + c] = f2bf(fmaxf(acc[a][bq][j], 0.f));
      } else {  // MODE 3: split-K
        if (blockIdx.y == 0) {
          #pragma unroll
          for (int j = 0; j < 4; j++) {
            long idx = (r0 + j) * (long)N + c;
            outf[idx] = resid[idx] + acc[a][bq][j];
          }
        } else {
          #pragma unroll
          for (int j = 0; j < 4; j++)
            pk[(r0 + j) * (long)N + c] = acc[a][bq][j];
        }
      }
    }
  }
}

// ---------------- fused flash attention (unchanged from R2) ----------------
__global__ __launch_bounds__(512)
void attn_kernel(const unsigned short* __restrict__ q, const unsigned short* __restrict__ k,
                 const unsigned short* __restrict__ vt, unsigned short* __restrict__ o) {
  __shared__ __align__(16) unsigned short Kt[2][32 * 128];
  __shared__ __align__(16) unsigned short VT[2][128 * 32];
  __shared__ __align__(16) unsigned short Pl[8][16 * 40];
  const int tid = threadIdx.x, w = tid >> 6, l = tid & 63;
  const int b = blockIdx.z, h = blockIdx.y, qb = blockIdx.x;
  const long base = ((long)(b * N_HEADS + h)) * SEQ * HEAD_DIM;
  const unsigned short* qp = q + base + (long)(qb * 128) * HEAD_DIM;
  const unsigned short* kp = k + base;
  const unsigned short* vp = vt + base;   // [hd][S]
  const int hi = l >> 4, lr = l & 15;

  bf16x8 qf[4];
  #pragma unroll
  for (int kc = 0; kc < 4; kc++)
    qf[kc] = *(const bf16x8*)&qp[(w * 16 + lr) * HEAD_DIM + kc * 32 + hi * 8];

  f32x4 oacc[8] = {};
  float mrow[4], lsum[4];
  #pragma unroll
  for (int j = 0; j < 4; j++) { mrow[j] = -1e30f; lsum[j] = 0.f; }

  const float sc = 0.08838834764831845f;  // 1/sqrt(128)
  const int NT = SEQ / 32;

  const int krow = w * 4 + hi;
  const long ksrc_off = (long)krow * 256 + (((l & 15) * 16) ^ ((krow & 7) << 4));
  const int vd = w * 16 + (l >> 2);
  const long vsrc_off = (long)vd * (SEQ * 2) + (l & 3) * 16;

  gload_lds16((const char*)kp + ksrc_off, (char*)Kt[0] + w * 1024);
  gload_lds16((const char*)vp + vsrc_off, (char*)VT[0] + w * 1024);

  int cur = 0;
  for (int t = 0; t < NT; t++) {
    if (t < NT - 1) {
      const long k0b = (long)(t + 1) * 64;
      gload_lds16((const char*)kp + (t + 1) * (32 * 256) + ksrc_off, (char*)Kt[cur ^ 1] + w * 1024);
      gload_lds16((const char*)vp + k0b + vsrc_off,                  (char*)VT[cur ^ 1] + w * 1024);
      VMW(2);
    } else {
      VMW(0);
    }
    __builtin_amdgcn_s_barrier();

    const unsigned short* Kc = Kt[cur];
    const unsigned short* Vc = VT[cur];

    f32x4 s[2] = {};
    #pragma unroll
    for (int kt = 0; kt < 2; kt++) {
      int kcol = kt * 16 + lr;
      #pragma unroll
      for (int kc = 0; kc < 4; kc++) {
        int off = (kc * 64 + hi * 16) ^ ((kcol & 7) << 4);
        bf16x8 kf = *(const bf16x8*)((const char*)Kc + kcol * 256 + off);
        s[kt] = __builtin_amdgcn_mfma_f32_16x16x32_bf16(qf[kc], kf, s[kt], 0, 0, 0);
      }
    }
    #pragma unroll
    for (int kt = 0; kt < 2; kt++)
      #pragma unroll
      for (int j = 0; j < 4; j++) s[kt][j] *= sc;

    float pm[4];
    #pragma unroll
    for (int j = 0; j < 4; j++) pm[j] = fmaxf(s[0][j], s[1][j]);
    #pragma unroll
    for (int m = 1; m < 16; m <<= 1)
      #pragma unroll
      for (int j = 0; j < 4; j++) pm[j] = fmaxf(pm[j], __shfl_xor(pm[j], m));
    int need = 0;
    #pragma unroll
    for (int j = 0; j < 4; j++) need |= (pm[j] > mrow[j] + 8.0f);
    if (__any(need)) {
      #pragma unroll
      for (int j = 0; j < 4; j++) {
        float nm = fmaxf(mrow[j], pm[j]);
        float alpha = __expf(mrow[j] - nm);
        mrow[j] = nm;
        lsum[j] *= alpha;
        #pragma unroll
        for (int n = 0; n < 8; n++) oacc[n][j] *= alpha;
      }
    }
    float p0[4], p1[4], ps[4];
    #pragma unroll
    for (int j = 0; j < 4; j++) {
      p0[j] = __expf(s[0][j] - mrow[j]);
      p1[j] = __expf(s[1][j] - mrow[j]);
      ps[j] = p0[j] + p1[j];
    }
    #pragma unroll
    for (int m = 1; m < 16; m <<= 1)
      #pragma unroll
      for (int j = 0; j < 4; j++) ps[j] += __shfl_xor(ps[j], m);
    #pragma unroll
    for (int j = 0; j < 4; j++) lsum[j] += ps[j];

    unsigned short* Pw = Pl[w];
    #pragma unroll
    for (int j = 0; j < 4; j++) {
      int qr = hi * 4 + j;
      Pw[qr * 40 + lr]      = f2bf(p0[j]);
      Pw[qr * 40 + 16 + lr] = f2bf(p1[j]);
    }
    bf16x8 pa = *(const bf16x8*)&Pw[lr * 40 + hi * 8];
    #pragma unroll
    for (int n = 0; n < 8; n++) {
      bf16x8 vf = *(const bf16x8*)&Vc[(n * 16 + lr) * 32 + hi * 8];
      oacc[n] = __builtin_amdgcn_mfma_f32_16x16x32_bf16(pa, vf, oacc[n], 0, 0, 0);
    }
    __builtin_amdgcn_s_barrier();
    cur ^= 1;
  }

  float rls[4];
  #pragma unroll
  for (int j = 0; j < 4; j++) rls[j] = 1.f / lsum[j];
  #pragma unroll
  for (int n = 0; n < 8; n++)
    #pragma unroll
    for (int j = 0; j < 4; j++) {
      int sp = qb * 128 + w * 16 + hi * 4 + j;
      int d = n * 16 + lr;
      o[((long)b * SEQ + sp) * D_MODEL + h * HEAD_DIM + d] = f2bf(oacc[n][j] * rls[j]);
    }
}

// ---------------- launcher ----------------
extern "C" void kernel_launch(void* const* d_in, const int* in_sizes, int n_in,
                              void* d_out, int out_size, void* d_ws, size_t ws_size,
                              hipStream_t stream) {
  (void)in_sizes; (void)n_in; (void)out_size; (void)ws_size;
  const float* x   = (const float*)d_in[0];
  const float* wq  = (const float*)d_in[1];
  const float* wk  = (const float*)d_in[2];
  const float* wv  = (const float*)d_in[3];
  const float* wo  = (const float*)d_in[4];
  const float* wup = (const float*)d_in[5];
  const float* wdn = (const float*)d_in[6];
  const float* g1  = (const float*)d_in[7];
  const float* b1  = (const float*)d_in[8];
  const float* g2  = (const float*)d_in[9];
  const float* b2  = (const float*)d_in[10];
  float* out = (float*)d_out;

  char* ws = (char*)d_ws;
  size_t off = 0;
  unsigned short* wqkv = (unsigned short*)(ws + off); off += (size_t)3 * D_MODEL * D_MODEL * 2;
  unsigned short* wo_b = (unsigned short*)(ws + off); off += (size_t)D_MODEL * D_MODEL * 2;
  unsigned short* wup_b = (unsigned short*)(ws + off); off += (size_t)DFF_DIM * D_MODEL * 2;
  unsigned short* wdn_b = (unsigned short*)(ws + off); off += (size_t)DFF_DIM * D_MODEL * 2;
  unsigned short* h_b  = (unsigned short*)(ws + off); off += (size_t)M_TOK * D_MODEL * 2;
  unsigned short* q_b  = (unsigned short*)(ws + off); off += (size_t)M_TOK * D_MODEL * 2;
  unsigned short* k_b  = (unsigned short*)(ws + off); off += (size_t)M_TOK * D_MODEL * 2;
  unsigned short* v_b  = (unsigned short*)(ws + off); off += (size_t)M_TOK * D_MODEL * 2;  // V^T [B,H,hd,S]
  unsigned short* ao_b = (unsigned short*)(ws + off); off += (size_t)M_TOK * D_MODEL * 2;
  float* x1            = (float*)(ws + off);          off += (size_t)M_TOK * D_MODEL * 4;
  unsigned short* ffu  = q_b;          // FF-up out: spans q_b..ao_b (67.1 MB), all dead then
  float* PKa = (float*)k_b;            // O-proj split-K partial: k_b+v_b = 33.55 MB exact, dead after attn
  float* PKd = (float*)wup_b;          // FF-down partial: wup_b = 33.55 MB exact, dead after FF-up

  const long nW = (long)D_MODEL * D_MODEL;      // 4.19M
  const long nU = (long)DFF_DIM * D_MODEL;      // 16.8M
  f2bf_kernel<<<nW / 1024, 256, 0, stream>>>(wq, wqkv, nW);
  f2bf_kernel<<<nW / 1024, 256, 0, stream>>>(wk, wqkv + nW, nW);
  f2bf_kernel<<<nW / 1024, 256, 0, stream>>>(wv, wqkv + 2 * nW, nW);
  f2bf_kernel<<<nW / 1024, 256, 0, stream>>>(wo, wo_b, nW);
  f2bf_kernel<<<nU / 1024, 256, 0, stream>>>(wup, wup_b, nU);
  f2bf_kernel<<<nU / 1024, 256, 0, stream>>>(wdn, wdn_b, nU);

  ln_kernel<<<M_TOK, 256, 0, stream>>>(x, g1, b1, h_b);

  // QKV: M=4096, N=6144, K=2048 -> 24x16 = 384 tiles
  gemm256<0><<<dim3(384, 1), 512, 0, stream>>>(h_b, wqkv, 3 * D_MODEL, D_MODEL, D_MODEL,
                                               nullptr, nullptr, nullptr, q_b, k_b, v_b);

  attn_kernel<<<dim3(SEQ / 128, N_HEADS, BATCH), 512, 0, stream>>>(q_b, k_b, v_b, ao_b);

  // O-proj: N=2048, K=2048, split-K=2 (Kext=1024); y0 -> x1 = x + acc, y1 -> PKa
  gemm256<3><<<dim3(128, 2), 512, 0, stream>>>(ao_b, wo_b, D_MODEL, D_MODEL, D_MODEL / 2,
                                               x, x1, PKa, nullptr, nullptr, nullptr);
  addk_kernel<<<(M_TOK * D_MODEL) / 1024, 256, 0, stream>>>(x1, PKa);

  ln_kernel<<<M_TOK, 256, 0, stream>>>(x1, g2, b2, h_b);

  // FF-up: N=8192, K=2048 -> 32x16 = 512 tiles
  gemm256<2><<<dim3(512, 1), 512, 0, stream>>>(h_b, wup_b, DFF_DIM, D_MODEL, D_MODEL,
                                               nullptr, nullptr, nullptr, ffu, nullptr, nullptr);

  // FF-down: N=2048, K=8192, split-K=2 (Kext=4096); y0 -> out = x1 + acc, y1 -> PKd
  gemm256<3><<<dim3(128, 2), 512, 0, stream>>>(ffu, wdn_b, D_MODEL, DFF_DIM, DFF_DIM / 2,
                                               x1, out, PKd, nullptr, nullptr, nullptr);
  addk_kernel<<<(M_TOK * D_MODEL) / 1024, 256, 0, stream>>>(out, PKd);
}

// Round 13
// 787.809 us; speedup vs baseline: 1.4957x; 1.1196x over previous
//
#include <hip/hip_runtime.h>

// TransformerBlock on MI355X (gfx950).
// R12 (resubmit): attn fixes — VT XOR-swizzle (kills 4-way PV conflict), softmax
// VALU cut (per-lane deferred lsum, reduce-free defer-max check, sc folded into exp).
// GEMMs unchanged from R8 (256^2 8-phase BK=64, vmcnt(6), split-K for O/FF-down).

#define D_MODEL 2048
#define N_HEADS 16
#define HEAD_DIM 128
#define DFF_DIM 8192
#define BATCH 2
#define SEQ 2048
#define M_TOK (BATCH*SEQ)  // 4096 tokens

typedef __attribute__((ext_vector_type(8))) __bf16 bf16x8;
typedef __attribute__((ext_vector_type(4))) float f32x4;

struct FalseT { static constexpr bool value = false; };
struct TrueT  { static constexpr bool value = true;  };

__device__ __forceinline__ unsigned short f2bf(float f) {
  union { float f; unsigned u; } v; v.f = f;
  unsigned r = v.u + 0x7fffu + ((v.u >> 16) & 1u);   // RNE
  return (unsigned short)(r >> 16);
}

__device__ __forceinline__ void gload_lds16(const void* g, void* l) {
  __builtin_amdgcn_global_load_lds(
      (const __attribute__((address_space(1))) unsigned int*)g,
      (__attribute__((address_space(3))) unsigned int*)l, 16, 0, 0);
}

#define BAR __builtin_amdgcn_s_barrier()
#define LG0 asm volatile("s_waitcnt lgkmcnt(0)" ::: "memory")
#define VMW(n) asm volatile("s_waitcnt vmcnt(" #n ")" ::: "memory")
#define PRIO1 __builtin_amdgcn_s_setprio(1)
#define PRIO0 __builtin_amdgcn_s_setprio(0)

// ---------------- fp32 -> bf16 convert ----------------
__global__ __launch_bounds__(256)
void f2bf_kernel(const float* __restrict__ in, unsigned short* __restrict__ out, long n) {
  long i = ((long)blockIdx.x * 256 + threadIdx.x) * 4;
  if (i < n) {
    float4 v = *(const float4*)&in[i];
    ushort4 r;
    r.x = f2bf(v.x); r.y = f2bf(v.y); r.z = f2bf(v.z); r.w = f2bf(v.w);
    *(ushort4*)&out[i] = r;
  }
}

// ---------------- dst[i] += src[i] (fp32, float4) ----------------
__global__ __launch_bounds__(256)
void addk_kernel(float* __restrict__ dst, const float* __restrict__ src) {
  long i = ((long)blockIdx.x * 256 + threadIdx.x) * 4;
  float4 d = *(float4*)&dst[i];
  float4 s = *(const float4*)&src[i];
  d.x += s.x; d.y += s.y; d.z += s.z; d.w += s.w;
  *(float4*)&dst[i] = d;
}

// ---------------- LayerNorm (row=2048 fp32) -> bf16 ----------------
__global__ __launch_bounds__(256)
void ln_kernel(const float* __restrict__ x, const float* __restrict__ g,
               const float* __restrict__ b, unsigned short* __restrict__ out) {
  const int row = blockIdx.x, t = threadIdx.x;
  const float* xr = x + (long)row * D_MODEL;
  float4 v0 = *(const float4*)&xr[t * 8];
  float4 v1 = *(const float4*)&xr[t * 8 + 4];
  float s  = v0.x + v0.y + v0.z + v0.w + v1.x + v1.y + v1.z + v1.w;
  float ss = v0.x*v0.x + v0.y*v0.y + v0.z*v0.z + v0.w*v0.w
           + v1.x*v1.x + v1.y*v1.y + v1.z*v1.z + v1.w*v1.w;
  #pragma unroll
  for (int m = 1; m < 64; m <<= 1) { s += __shfl_xor(s, m); ss += __shfl_xor(ss, m); }
  __shared__ float red[8];
  if ((t & 63) == 0) { red[t >> 6] = s; red[4 + (t >> 6)] = ss; }
  __syncthreads();
  s  = red[0] + red[1] + red[2] + red[3];
  ss = red[4] + red[5] + red[6] + red[7];
  const float mu = s * (1.f / D_MODEL);
  const float var = ss * (1.f / D_MODEL) - mu * mu;
  const float rs = rsqrtf(var + 1e-5f);
  float xv[8];
  xv[0]=v0.x; xv[1]=v0.y; xv[2]=v0.z; xv[3]=v0.w; xv[4]=v1.x; xv[5]=v1.y; xv[6]=v1.z; xv[7]=v1.w;
  #pragma unroll
  for (int j = 0; j < 8; j++) {
    int c = t * 8 + j;
    out[(long)row * D_MODEL + c] = f2bf((xv[j] - mu) * rs * g[c] + b[c]);
  }
}

// ---------------- 256x256 8-phase GEMM, BK=64 (unchanged from R8) ----------------
// Schedule/ledger comments: see R8. MODE 0: QKV scatter; MODE 2: relu->bf16;
// MODE 3: split-K via blockIdx.y (y0: outf=resid+acc, y1: pk=acc).
template<int MODE>
__global__ __launch_bounds__(512, 2)
void gemm256(const unsigned short* __restrict__ A, const unsigned short* __restrict__ Bt,
             int N, int Kstride, int Kext,
             const float* __restrict__ resid, float* __restrict__ outf,
             float* __restrict__ pk,
             unsigned short* __restrict__ ob0, unsigned short* __restrict__ ob1,
             unsigned short* __restrict__ ob2) {
  __shared__ __align__(16) char ldsc[131072];
  const int tid = threadIdx.x;
  const int w  = tid >> 6, l = tid & 63;
  const int wm = w >> 2, wn = w & 3;
  const int lr = l & 15, hi = l >> 4;

  const int cpx = (int)gridDim.x >> 3;
  const int tile = ((int)blockIdx.x & 7) * cpx + ((int)blockIdx.x >> 3);
  const int ty = tile & 15;          // grid_m = 16 (M = 4096)
  const int tx = tile >> 4;
  const long m0 = (long)ty * 256;
  const long n0 = (long)tx * 256;
  const long koff = (long)blockIdx.y * Kext;

  f32x4 acc[8][4] = {};
  bf16x8 a_r[8], b0_r[4], b1_r[4];

  const int trow = tid >> 3;                              // 0..63
  const int tcol = ((tid & 7) * 16) ^ ((trow & 7) << 4);  // byte in 128B row
  const char* pA = (const char*)A + ((m0 + trow) * (long)Kstride + koff) * 2 + tcol;
  const char* pB = (const char*)Bt + ((n0 + trow) * (long)Kstride + koff) * 2 + tcol;
  const size_t rowK = (size_t)Kstride * 2;                // bytes per row

  auto STGA = [&](int d, int h, int kt) {   // one half-tile = 2 gloads
    const char* s = pA + (size_t)(h * 128) * rowK + (size_t)kt * 128;
    char* dst = ldsc + d * 32768 + h * 16384 + w * 1024;
    gload_lds16(s, dst);
    gload_lds16(s + 64 * rowK, dst + 8192);
  };
  auto STGB = [&](int d, int h, int kt) {
    const char* s = pB + (size_t)(h * 128) * rowK + (size_t)kt * 128;
    char* dst = ldsc + 65536 + d * 32768 + h * 16384 + w * 1024;
    gload_lds16(s, dst);
    gload_lds16(s + 64 * rowK, dst + 8192);
  };

  const int xor0 = (hi * 16) ^ ((lr & 7) << 4);
  const int xor1 = (64 + hi * 16) ^ ((lr & 7) << 4);
  const char* lA0 = ldsc + wm * 16384 + lr * 128 + xor0;
  const char* lA1 = ldsc + wm * 16384 + lr * 128 + xor1;
  const char* lB0 = ldsc + 65536 + (wn >> 1) * 16384 + (wn & 1) * 8192 + lr * 128 + xor0;
  const char* lB1 = ldsc + 65536 + (wn >> 1) * 16384 + (wn & 1) * 8192 + lr * 128 + xor1;

  auto LDA = [&](int d, int mh) {
    #pragma unroll
    for (int mi = 0; mi < 4; mi++) {
      a_r[mi * 2 + 0] = *(const bf16x8*)(lA0 + d * 32768 + mh * 8192 + mi * 2048);
      a_r[mi * 2 + 1] = *(const bf16x8*)(lA1 + d * 32768 + mh * 8192 + mi * 2048);
    }
  };
  auto LDB = [&](int d, int nh, bf16x8* br) {
    #pragma unroll
    for (int ni = 0; ni < 2; ni++) {
      br[ni * 2 + 0] = *(const bf16x8*)(lB0 + d * 32768 + nh * 4096 + ni * 2048);
      br[ni * 2 + 1] = *(const bf16x8*)(lB1 + d * 32768 + nh * 4096 + ni * 2048);
    }
  };
  auto MF = [&](int mh, int nh, const bf16x8* br) {
    PRIO1;
    #pragma unroll
    for (int mi = 0; mi < 4; mi++)
      #pragma unroll
      for (int ni = 0; ni < 2; ni++) {
        f32x4 c = acc[mh * 4 + mi][nh * 2 + ni];
        c = __builtin_amdgcn_mfma_f32_16x16x32_bf16(a_r[mi * 2 + 0], br[ni * 2 + 0], c, 0, 0, 0);
        c = __builtin_amdgcn_mfma_f32_16x16x32_bf16(a_r[mi * 2 + 1], br[ni * 2 + 1], c, 0, 0, 0);
        acc[mh * 4 + mi][nh * 2 + ni] = c;
      }
    PRIO0;
  };

  STGA(0, 0, 0); STGA(0, 1, 0); STGB(0, 0, 0); STGB(0, 1, 0);
  STGB(1, 0, 1); STGB(1, 1, 1); STGA(1, 0, 1);
  VMW(6); BAR;

  auto iter = [&](int e, auto lastc) {
    constexpr bool L = decltype(lastc)::value;
    LDA(0, 0); LDB(0, 0, b0_r); STGA(1, 1, e + 1);
    BAR; LG0; MF(0, 0, b0_r); BAR;
    LDB(0, 1, b1_r); if constexpr (!L) STGB(0, 0, e + 2);
    BAR; LG0; MF(0, 1, b1_r); BAR;
    LDA(0, 1); if constexpr (!L) STGB(0, 1, e + 2);
    BAR; LG0; MF(1, 0, b0_r); BAR;
    if constexpr (!L) { STGA(0, 0, e + 2); VMW(6); } else { VMW(0); }
    BAR; MF(1, 1, b1_r); BAR;
    LDA(1, 0); LDB(1, 0, b0_r); if constexpr (!L) STGA(0, 1, e + 2);
    BAR; LG0; MF(0, 0, b0_r); BAR;
    LDB(1, 1, b1_r); if constexpr (!L) STGB(1, 0, e + 3);
    BAR; LG0; MF(0, 1, b1_r); BAR;
    LDA(1, 1); if constexpr (!L) STGB(1, 1, e + 3);
    BAR; LG0; MF(1, 0, b0_r); BAR;
    if constexpr (!L) { STGA(1, 0, e + 3); VMW(6); }
    BAR; MF(1, 1, b1_r); BAR;
  };

  const int NITER = Kext >> 7;   // 2 K-tiles (BK=64) per iteration
  for (int it = 0; it < NITER - 1; it++) iter(2 * it, FalseT{});
  iter(2 * (NITER - 1), TrueT{});

  #pragma unroll
  for (int a = 0; a < 8; a++) {
    const int mh = a >> 2, mi = a & 3;
    #pragma unroll
    for (int bq = 0; bq < 4; bq++) {
      const int nh = bq >> 1, ni = bq & 1;
      long c  = n0 + wn * 64 + nh * 32 + ni * 16 + lr;
      long r0 = m0 + wm * 128 + mh * 64 + mi * 16 + hi * 4;
      if (MODE == 0) {
        int which = (int)(c >> 11);
        int cc = (int)(c & 2047);
        int hh = cc >> 7, dd = cc & 127;
        int bb = (int)(r0 >> 11), sp = (int)(r0 & 2047);
        if (which == 2) {
          ushort4 pkv;
          pkv.x = f2bf(acc[a][bq][0]); pkv.y = f2bf(acc[a][bq][1]);
          pkv.z = f2bf(acc[a][bq][2]); pkv.w = f2bf(acc[a][bq][3]);
          *(ushort4*)&ob2[((long)(bb * N_HEADS + hh) * HEAD_DIM + dd) * SEQ + sp] = pkv;
        } else {
          #pragma unroll
          for (int j = 0; j < 4; j++) {
            long idx = ((long)(bb * N_HEADS + hh) * SEQ + sp + j) * HEAD_DIM + dd;
            unsigned short bv = f2bf(acc[a][bq][j]);
            if (which == 0) ob0[idx] = bv; else ob1[idx] = bv;
          }
        }
      } else if (MODE == 2) {
        #pragma unroll
        for (int j = 0; j < 4; j++)
          ob0[(r0 + j) * (long)N + c] = f2bf(fmaxf(acc[a][bq][j], 0.f));
      } else {  // MODE 3: split-K
        if (blockIdx.y == 0) {
          #pragma unroll
          for (int j = 0; j < 4; j++) {
            long idx = (r0 + j) * (long)N + c;
            outf[idx] = resid[idx] + acc[a][bq][j];
          }
        } else {
          #pragma unroll
          for (int j = 0; j < 4; j++)
            pk[(r0 + j) * (long)N + c] = acc[a][bq][j];
        }
      }
    }
  }
}

// ---------------- fused flash attention (R12) ----------------
// grid (S/128, H, B), 512 thr (8 waves). KV tiles of 32, double-buffered.
// Kt[2][32][128] XOR-swizzled (unchanged). VT[2][128][32] swizzled: 16B slot
// ^= (row>>1)&3, pre-applied on staging source, applied on read — each 8-lane
// read group hits 8 distinct 16B chunks mod 8 (was 4-way conflict).
// Softmax: defer-max with per-lane threshold check (no per-tile pm reduce),
// per-lane deferred lsum (one 16-lane reduce at end), sc folded into exp.
__global__ __launch_bounds__(512)
void attn_kernel(const unsigned short* __restrict__ q, const unsigned short* __restrict__ k,
                 const unsigned short* __restrict__ vt, unsigned short* __restrict__ o) {
  __shared__ __align__(16) unsigned short Kt[2][32 * 128];
  __shared__ __align__(16) unsigned short VT[2][128 * 32];
  __shared__ __align__(16) unsigned short Pl[8][16 * 40];
  const int tid = threadIdx.x, w = tid >> 6, l = tid & 63;
  const int b = blockIdx.z, h = blockIdx.y, qb = blockIdx.x;
  const long base = ((long)(b * N_HEADS + h)) * SEQ * HEAD_DIM;
  const unsigned short* qp = q + base + (long)(qb * 128) * HEAD_DIM;
  const unsigned short* kp = k + base;
  const unsigned short* vp = vt + base;   // [hd][S]
  const int hi = l >> 4, lr = l & 15;

  bf16x8 qf[4];
  #pragma unroll
  for (int kc = 0; kc < 4; kc++)
    qf[kc] = *(const bf16x8*)&qp[(w * 16 + lr) * HEAD_DIM + kc * 32 + hi * 8];

  f32x4 oacc[8] = {};
  float mrow[4], msc[4], lsump[4];
  #pragma unroll
  for (int j = 0; j < 4; j++) { mrow[j] = -1e30f; msc[j] = -8.8388e28f; lsump[j] = 0.f; }

  const float sc = 0.08838834764831845f;   // 1/sqrt(128)
  const float THRraw = 90.50966799f;       // 8 / sc
  const int NT = SEQ / 32;

  // K staging (unchanged): wave covers rows w*4..w*4+3, pre-swizzled source
  const int krow = w * 4 + hi;
  const long ksrc_off = (long)krow * 256 + (((l & 15) * 16) ^ ((krow & 7) << 4));
  // V staging: rows vd = w*16 + (l>>2); source 16B-slot = (l&3) ^ ((vd>>1)&3)
  //   (vd>>1)&3 == (l>>3)&3 since w*8 ≡ 0 mod 4
  const int vd = w * 16 + (l >> 2);
  const int vslot = (l & 3) ^ ((l >> 3) & 3);
  const long vsrc_off = (long)vd * (SEQ * 2) + vslot * 16;
  // PV read slot (per-lane const): hi ^ ((row>>1)&3) with row = n*16+lr
  const int rdslot = hi ^ ((lr >> 1) & 3);

  gload_lds16((const char*)kp + ksrc_off, (char*)Kt[0] + w * 1024);
  gload_lds16((const char*)vp + vsrc_off, (char*)VT[0] + w * 1024);

  int cur = 0;
  for (int t = 0; t < NT; t++) {
    if (t < NT - 1) {
      const long k0b = (long)(t + 1) * 64;
      gload_lds16((const char*)kp + (t + 1) * (32 * 256) + ksrc_off, (char*)Kt[cur ^ 1] + w * 1024);
      gload_lds16((const char*)vp + k0b + vsrc_off,                  (char*)VT[cur ^ 1] + w * 1024);
      VMW(2);
    } else {
      VMW(0);
    }
    __builtin_amdgcn_s_barrier();

    const unsigned short* Kc = Kt[cur];
    const unsigned short* Vc = VT[cur];

    // QK^T (raw, unscaled): S[q][kcol], 2 col-tiles of 16
    f32x4 s[2] = {};
    #pragma unroll
    for (int kt = 0; kt < 2; kt++) {
      int kcol = kt * 16 + lr;
      #pragma unroll
      for (int kc = 0; kc < 4; kc++) {
        int off = (kc * 64 + hi * 16) ^ ((kcol & 7) << 4);
        bf16x8 kf = *(const bf16x8*)((const char*)Kc + kcol * 256 + off);
        s[kt] = __builtin_amdgcn_mfma_f32_16x16x32_bf16(qf[kc], kf, s[kt], 0, 0, 0);
      }
    }

    // defer-max: per-lane threshold check, no reduce on fast path
    int need = 0;
    #pragma unroll
    for (int j = 0; j < 4; j++)
      need |= (s[0][j] > mrow[j] + THRraw) | (s[1][j] > mrow[j] + THRraw);
    if (__any(need)) {
      float pm[4];
      #pragma unroll
      for (int j = 0; j < 4; j++) pm[j] = fmaxf(s[0][j], s[1][j]);
      #pragma unroll
      for (int m = 1; m < 16; m <<= 1)
        #pragma unroll
        for (int j = 0; j < 4; j++) pm[j] = fmaxf(pm[j], __shfl_xor(pm[j], m));
      #pragma unroll
      for (int j = 0; j < 4; j++) {
        float nm = fmaxf(mrow[j], pm[j]);
        float alpha = __expf((mrow[j] - nm) * sc);
        mrow[j] = nm; msc[j] = nm * sc;
        lsump[j] *= alpha;
        #pragma unroll
        for (int n = 0; n < 8; n++) oacc[n][j] *= alpha;
      }
    }
    float p0[4], p1[4];
    #pragma unroll
    for (int j = 0; j < 4; j++) {
      p0[j] = __expf(fmaf(s[0][j], sc, -msc[j]));
      p1[j] = __expf(fmaf(s[1][j], sc, -msc[j]));
      lsump[j] += p0[j] + p1[j];
    }

    // P -> per-wave LDS (bf16), stride 40
    unsigned short* Pw = Pl[w];
    #pragma unroll
    for (int j = 0; j < 4; j++) {
      int qr = hi * 4 + j;
      Pw[qr * 40 + lr]      = f2bf(p0[j]);
      Pw[qr * 40 + 16 + lr] = f2bf(p1[j]);
    }
    // PV: O[q][d] += P[16x32] * V[32x128], VT reads swizzled
    bf16x8 pa = *(const bf16x8*)&Pw[lr * 40 + hi * 8];
    #pragma unroll
    for (int n = 0; n < 8; n++) {
      bf16x8 vf = *(const bf16x8*)((const char*)Vc + (n * 16 + lr) * 64 + rdslot * 16);
      oacc[n] = __builtin_amdgcn_mfma_f32_16x16x32_bf16(pa, vf, oacc[n], 0, 0, 0);
    }
    __builtin_amdgcn_s_barrier();
    cur ^= 1;
  }

  // one final 16-lane reduce of the deferred lsum
  #pragma unroll
  for (int m = 1; m < 16; m <<= 1)
    #pragma unroll
    for (int j = 0; j < 4; j++) lsump[j] += __shfl_xor(lsump[j], m);
  float rls[4];
  #pragma unroll
  for (int j = 0; j < 4; j++) rls[j] = 1.f / lsump[j];
  #pragma unroll
  for (int n = 0; n < 8; n++)
    #pragma unroll
    for (int j = 0; j < 4; j++) {
      int sp = qb * 128 + w * 16 + hi * 4 + j;
      int d = n * 16 + lr;
      o[((long)b * SEQ + sp) * D_MODEL + h * HEAD_DIM + d] = f2bf(oacc[n][j] * rls[j]);
    }
}

// ---------------- launcher ----------------
extern "C" void kernel_launch(void* const* d_in, const int* in_sizes, int n_in,
                              void* d_out, int out_size, void* d_ws, size_t ws_size,
                              hipStream_t stream) {
  (void)in_sizes; (void)n_in; (void)out_size; (void)ws_size;
  const float* x   = (const float*)d_in[0];
  const float* wq  = (const float*)d_in[1];
  const float* wk  = (const float*)d_in[2];
  const float* wv  = (const float*)d_in[3];
  const float* wo  = (const float*)d_in[4];
  const float* wup = (const float*)d_in[5];
  const float* wdn = (const float*)d_in[6];
  const float* g1  = (const float*)d_in[7];
  const float* b1  = (const float*)d_in[8];
  const float* g2  = (const float*)d_in[9];
  const float* b2  = (const float*)d_in[10];
  float* out = (float*)d_out;

  char* ws = (char*)d_ws;
  size_t off = 0;
  unsigned short* wqkv = (unsigned short*)(ws + off); off += (size_t)3 * D_MODEL * D_MODEL * 2;
  unsigned short* wo_b = (unsigned short*)(ws + off); off += (size_t)D_MODEL * D_MODEL * 2;
  unsigned short* wup_b = (unsigned short*)(ws + off); off += (size_t)DFF_DIM * D_MODEL * 2;
  unsigned short* wdn_b = (unsigned short*)(ws + off); off += (size_t)DFF_DIM * D_MODEL * 2;
  unsigned short* h_b  = (unsigned short*)(ws + off); off += (size_t)M_TOK * D_MODEL * 2;
  unsigned short* q_b  = (unsigned short*)(ws + off); off += (size_t)M_TOK * D_MODEL * 2;
  unsigned short* k_b  = (unsigned short*)(ws + off); off += (size_t)M_TOK * D_MODEL * 2;
  unsigned short* v_b  = (unsigned short*)(ws + off); off += (size_t)M_TOK * D_MODEL * 2;  // V^T [B,H,hd,S]
  unsigned short* ao_b = (unsigned short*)(ws + off); off += (size_t)M_TOK * D_MODEL * 2;
  float* x1            = (float*)(ws + off);          off += (size_t)M_TOK * D_MODEL * 4;
  unsigned short* ffu  = q_b;          // FF-up out: spans q_b..ao_b (67.1 MB), all dead then
  float* PKa = (float*)k_b;            // O-proj split-K partial: k_b+v_b = 33.55 MB exact, dead after attn
  float* PKd = (float*)wup_b;          // FF-down partial: wup_b = 33.55 MB exact, dead after FF-up

  const long nW = (long)D_MODEL * D_MODEL;      // 4.19M
  const long nU = (long)DFF_DIM * D_MODEL;      // 16.8M
  f2bf_kernel<<<nW / 1024, 256, 0, stream>>>(wq, wqkv, nW);
  f2bf_kernel<<<nW / 1024, 256, 0, stream>>>(wk, wqkv + nW, nW);
  f2bf_kernel<<<nW / 1024, 256, 0, stream>>>(wv, wqkv + 2 * nW, nW);
  f2bf_kernel<<<nW / 1024, 256, 0, stream>>>(wo, wo_b, nW);
  f2bf_kernel<<<nU / 1024, 256, 0, stream>>>(wup, wup_b, nU);
  f2bf_kernel<<<nU / 1024, 256, 0, stream>>>(wdn, wdn_b, nU);

  ln_kernel<<<M_TOK, 256, 0, stream>>>(x, g1, b1, h_b);

  // QKV: M=4096, N=6144, K=2048 -> 24x16 = 384 tiles
  gemm256<0><<<dim3(384, 1), 512, 0, stream>>>(h_b, wqkv, 3 * D_MODEL, D_MODEL, D_MODEL,
                                               nullptr, nullptr, nullptr, q_b, k_b, v_b);

  attn_kernel<<<dim3(SEQ / 128, N_HEADS, BATCH), 512, 0, stream>>>(q_b, k_b, v_b, ao_b);

  // O-proj: N=2048, K=2048, split-K=2 (Kext=1024); y0 -> x1 = x + acc, y1 -> PKa
  gemm256<3><<<dim3(128, 2), 512, 0, stream>>>(ao_b, wo_b, D_MODEL, D_MODEL, D_MODEL / 2,
                                               x, x1, PKa, nullptr, nullptr, nullptr);
  addk_kernel<<<(M_TOK * D_MODEL) / 1024, 256, 0, stream>>>(x1, PKa);

  ln_kernel<<<M_TOK, 256, 0, stream>>>(x1, g2, b2, h_b);

  // FF-up: N=8192, K=2048 -> 32x16 = 512 tiles
  gemm256<2><<<dim3(512, 1), 512, 0, stream>>>(h_b, wup_b, DFF_DIM, D_MODEL, D_MODEL,
                                               nullptr, nullptr, nullptr, ffu, nullptr, nullptr);

  // FF-down: N=2048, K=8192, split-K=2 (Kext=4096); y0 -> out = x1 + acc, y1 -> PKd
  gemm256<3><<<dim3(128, 2), 512, 0, stream>>>(ffu, wdn_b, D_MODEL, DFF_DIM, DFF_DIM / 2,
                                               x1, out, PKd, nullptr, nullptr, nullptr);
  addk_kernel<<<(M_TOK * D_MODEL) / 1024, 256, 0, stream>>>(out, PKd);
}